// Round 4
// baseline (806.395 us; speedup 1.0000x reference)
//
#include <hip/hip_runtime.h>
#include <hip/hip_bf16.h>

// MLA forward, MI355X/gfx950.
// B=4, S=2048, D_MODEL=1024, H=16, D_H=64, D_HR=32, D_LATENT=256, d_qk=96.

typedef __attribute__((ext_vector_type(8))) __bf16 bf16x8;
typedef __attribute__((ext_vector_type(4))) float f32x4;
typedef __attribute__((ext_vector_type(4))) unsigned short us4;

#define DEV static __device__ __forceinline__

DEV unsigned short f2b(float f) {
  union { __hip_bfloat16 h; unsigned short u; } v;
  v.h = __float2bfloat16(f);
  return v.u;
}
DEV float b2f(unsigned short u) {
  union { unsigned short u; __hip_bfloat16 h; } v;
  v.u = u;
  return __bfloat162float(v.h);
}
DEV f32x4 mfma16(bf16x8 a, bf16x8 b, f32x4 c) {
  return __builtin_amdgcn_mfma_f32_16x16x32_bf16(a, b, c, 0, 0, 0);
}
DEV void load_lds16(const void* g, void* lds) {
  __builtin_amdgcn_global_load_lds((__attribute__((address_space(1))) void*)g,
                                   (__attribute__((address_space(3))) void*)lds,
                                   16, 0, 0);
}
DEV bf16x8 ones8() {
  union { unsigned short u[8]; bf16x8 v; } c;
#pragma unroll
  for (int i = 0; i < 8; ++i) c.u[i] = 0x3F80;  // bf16 1.0
  return c.v;
}
// LDS-only drain: does NOT touch vmcnt, so global_load_lds prefetch stays in flight.
#define LGKM_DRAIN() __asm__ volatile("s_waitcnt lgkmcnt(0)" ::: "memory")

// ---------------- convert x (fp32 -> bf16) ----------------
__global__ __launch_bounds__(256) void convert_x(const float* __restrict__ x,
                                                 unsigned short* __restrict__ xb) {
  long i = (long)(blockIdx.x * 256 + threadIdx.x) * 4;
  float4 v = *(const float4*)(x + i);
  us4 o = { f2b(v.x), f2b(v.y), f2b(v.z), f2b(v.w) };
  *(us4*)(xb + i) = o;
}

// ---------------- batched weight transpose: 8 weights in ONE dispatch ----------------
// W (K x N) fp32 -> WT (N x K) bf16. All K,N multiples of 32.
struct TWArgs { const float* W[8]; unsigned short* T[8]; };
__global__ __launch_bounds__(256) void transpose_w_all(TWArgs a) {
  int bid = blockIdx.x;
  // ranges: [0,256) DQ | [256,512) DKV | [512,544) KR | [544,800) UQ |
  //         [800,928) QR | [928,1184) UK | [1184,1440) UV | [1440,2464) O
  int g;
  if      (bid < 256)  g = 0;
  else if (bid < 512)  g = 1;
  else if (bid < 544)  g = 2;
  else if (bid < 800)  g = 3;
  else if (bid < 928)  g = 4;
  else if (bid < 1184) g = 5;
  else if (bid < 1440) g = 6;
  else                 g = 7;
  const int starts[8] = {0, 256, 512, 544, 800, 928, 1184, 1440};
  int local = bid - starts[g];
  int K = (g >= 3 && g <= 6) ? 256 : 1024;
  int N = (g < 2) ? 256 : (g == 2 ? 32 : (g == 4 ? 512 : 1024));
  int tilesX = N >> 5;
  int n0 = (local % tilesX) * 32, k0 = (local / tilesX) * 32;
  const float* W = a.W[g];
  unsigned short* WT = a.T[g];
  __shared__ float tile[32][33];
  int tx = threadIdx.x & 31, ty = threadIdx.x >> 5;
#pragma unroll
  for (int i = 0; i < 32; i += 8)
    tile[ty + i][tx] = W[(size_t)(k0 + ty + i) * N + n0 + tx];
  __syncthreads();
#pragma unroll
  for (int i = 0; i < 32; i += 8)
    WT[(size_t)(n0 + ty + i) * K + k0 + tx] = f2b(tile[tx][ty + i]);
}

// ---------------- fused RoPE: Qr in-place in C2, Kr C1->Krr ----------------
__global__ __launch_bounds__(256) void rope_qk(unsigned short* __restrict__ C2,
                                               const unsigned short* __restrict__ C1,
                                               unsigned short* __restrict__ Krr) {
  if (blockIdx.x < 8192) {
    int idx = blockIdx.x * 256 + threadIdx.x;   // 2^21 threads exact
    int i = idx & 15, h = (idx >> 4) & 15, s = (idx >> 8) & 2047, b = idx >> 19;
    long base = (long)(b * 2048 + s) * 1536 + 1024 + h * 32 + 2 * i;
    float x1 = b2f(C2[base]), x2 = b2f(C2[base + 1]);
    float inv = exp2f(-(float)i * 0.8304820237686285f);  // 10000^(-i/16)
    float ang = (float)s * inv;
    float c = cosf(ang), sn = sinf(ang);
    C2[base]     = f2b(x1 * c - x2 * sn);
    C2[base + 1] = f2b(x1 * sn + x2 * c);
  } else {
    int idx = (blockIdx.x - 8192) * 256 + threadIdx.x;   // 2^17 threads exact
    int i = idx & 15, s = (idx >> 4) & 2047, b = idx >> 15;
    long src = (long)(b * 2048 + s) * 544 + 512 + 2 * i;
    float x1 = b2f(C1[src]), x2 = b2f(C1[src + 1]);
    float inv = exp2f(-(float)i * 0.8304820237686285f);
    float ang = (float)s * inv;
    float c = cosf(ang), sn = sinf(ang);
    long dst = (long)(b * 2048 + s) * 32 + 2 * i;
    Krr[dst]     = f2b(x1 * c - x2 * sn);
    Krr[dst + 1] = f2b(x1 * sn + x2 * c);
  }
}

// ---------------- GEMM: C(M x N) = A(M x K, lda) @ Bt(N x K, ldb)^T ----------------
template <bool OUT_BF16>
__global__ __launch_bounds__(256) void gemm_bt(const unsigned short* __restrict__ A, int lda,
                                               const unsigned short* __restrict__ Bt, int ldb,
                                               void* __restrict__ Cv, int ldc, int N, int K) {
  __shared__ __align__(16) unsigned short As[128 * 32];
  __shared__ __align__(16) unsigned short Bs[128 * 32];
  const int t = threadIdx.x;
  const int w = t >> 6, lane = t & 63, ln = lane & 15, quad = lane >> 4;
  const int wr = w >> 1, wc = w & 1;
  const int bm0 = blockIdx.x * 128, bn0 = blockIdx.y * 128;
  const int srow = t >> 2;          // 0..63
  const int scol = (t & 3) * 8;     // 0,8,16,24
  f32x4 zero = {0.f, 0.f, 0.f, 0.f};
  f32x4 acc[4][4];
#pragma unroll
  for (int i = 0; i < 4; ++i)
#pragma unroll
    for (int j = 0; j < 4; ++j) acc[i][j] = zero;

  for (int k0 = 0; k0 < K; k0 += 32) {
#pragma unroll
    for (int r = 0; r < 2; ++r) {
      int arow = bm0 + r * 64 + srow;
      load_lds16(A + (long)arow * lda + k0 + scol, (char*)As + r * 4096 + w * 1024);
      int brow = bn0 + r * 64 + srow;
      if (brow > N - 1) brow = N - 1;  // clamp (garbage cols guarded at write)
      load_lds16(Bt + (long)brow * ldb + k0 + scol, (char*)Bs + r * 4096 + w * 1024);
    }
    __syncthreads();
    bf16x8 af[4], bf[4];
#pragma unroll
    for (int i = 0; i < 4; ++i)
      af[i] = *(const bf16x8*)(As + (wr * 64 + i * 16 + ln) * 32 + quad * 8);
#pragma unroll
    for (int j = 0; j < 4; ++j)
      bf[j] = *(const bf16x8*)(Bs + (wc * 64 + j * 16 + ln) * 32 + quad * 8);
#pragma unroll
    for (int i = 0; i < 4; ++i)
#pragma unroll
      for (int j = 0; j < 4; ++j) acc[i][j] = mfma16(af[i], bf[j], acc[i][j]);
    __syncthreads();
  }
#pragma unroll
  for (int i = 0; i < 4; ++i)
#pragma unroll
    for (int j = 0; j < 4; ++j)
#pragma unroll
      for (int r = 0; r < 4; ++r) {
        int row = bm0 + wr * 64 + i * 16 + quad * 4 + r;
        int col = bn0 + wc * 64 + j * 16 + ln;
        if (col < N) {
          if (OUT_BF16)
            ((unsigned short*)Cv)[(long)row * ldc + col] = f2b(acc[i][j][r]);
          else
            ((float*)Cv)[(long)row * ldc + col] = acc[i][j][r];
        }
      }
}

// ---------------- V GEMM with transposed epilogue: writes Vt[bh*64+d][s] directly ----------------
// A = c_kv (M x 256), Bt = W_UV^T (1024 x 256). N=1024 fixed. Kills transpose_v.
__global__ __launch_bounds__(256) void gemm_bt_vt(const unsigned short* __restrict__ A, int lda,
                                                  const unsigned short* __restrict__ Bt, int ldb,
                                                  unsigned short* __restrict__ Vt, int K) {
  __shared__ __align__(16) unsigned short As[128 * 32];
  __shared__ __align__(16) unsigned short Bs[128 * 32];
  const int t = threadIdx.x;
  const int w = t >> 6, lane = t & 63, ln = lane & 15, quad = lane >> 4;
  const int wr = w >> 1, wc = w & 1;
  const int bm0 = blockIdx.x * 128, bn0 = blockIdx.y * 128;
  const int srow = t >> 2, scol = (t & 3) * 8;
  f32x4 zero = {0.f, 0.f, 0.f, 0.f};
  f32x4 acc[4][4];
#pragma unroll
  for (int i = 0; i < 4; ++i)
#pragma unroll
    for (int j = 0; j < 4; ++j) acc[i][j] = zero;

  for (int k0 = 0; k0 < K; k0 += 32) {
#pragma unroll
    for (int r = 0; r < 2; ++r) {
      load_lds16(A + (long)(bm0 + r * 64 + srow) * lda + k0 + scol, (char*)As + r * 4096 + w * 1024);
      load_lds16(Bt + (long)(bn0 + r * 64 + srow) * ldb + k0 + scol, (char*)Bs + r * 4096 + w * 1024);
    }
    __syncthreads();
    bf16x8 af[4], bf[4];
#pragma unroll
    for (int i = 0; i < 4; ++i)
      af[i] = *(const bf16x8*)(As + (wr * 64 + i * 16 + ln) * 32 + quad * 8);
#pragma unroll
    for (int j = 0; j < 4; ++j)
      bf[j] = *(const bf16x8*)(Bs + (wc * 64 + j * 16 + ln) * 32 + quad * 8);
#pragma unroll
    for (int i = 0; i < 4; ++i)
#pragma unroll
      for (int j = 0; j < 4; ++j) acc[i][j] = mfma16(af[i], bf[j], acc[i][j]);
    __syncthreads();
  }
  // transposed epilogue: col = h*64+d; rows r=0..3 consecutive -> one 8B store per (i,j)
#pragma unroll
  for (int i = 0; i < 4; ++i)
#pragma unroll
    for (int j = 0; j < 4; ++j) {
      int col = bn0 + wc * 64 + j * 16 + ln;          // 0..1023 = h*64+d
      int row0 = bm0 + wr * 64 + i * 16 + quad * 4;   // 4 consecutive seq rows, same b
      int b = row0 >> 11, sl = row0 & 2047;
      us4 pk = { f2b(acc[i][j][0]), f2b(acc[i][j][1]), f2b(acc[i][j][2]), f2b(acc[i][j][3]) };
      *(us4*)(Vt + ((size_t)(b * 16) * 64 + col) * 2048 + sl) = pk;  // (b*16+h)*64+d == b*1024+col
    }
}

// ---------------- Flash attention v3 ----------------
// grid (16, 64), qi = 15-x (LPT). 40KB LDS -> 4 blocks/CU -> ALL 1024 blocks co-resident.
// Kr read straight from global (L2-hot, shared by 16 heads), issued BEFORE the
// stage() DMAs so the FIFO vmcnt wait on Kr doesn't drain the prefetch.
// P roundtrip uses lgkm-only waitcnt (vmcnt stays in flight).
__global__ __launch_bounds__(256, 4) void flash_attn(const unsigned short* __restrict__ C2,
                                                     const unsigned short* __restrict__ C3,
                                                     const unsigned short* __restrict__ Krr,
                                                     const unsigned short* __restrict__ Vt,
                                                     unsigned short* __restrict__ Oa) {
  __shared__ __align__(16) unsigned short Ks[2][4096];   // 64 keys x 64 dims (swizzled 16B chunks)
  __shared__ __align__(16) unsigned short Vs[2][4096];   // 64 d    x 64 keys
  __shared__ __align__(16) unsigned short Ps[4][1024];   // per-wave P: 16 q x 64 keys

  const int tid = threadIdx.x;
  const int w = tid >> 6, lane = tid & 63, ln = lane & 15, quad = lane >> 4;
  const int bh = blockIdx.y, b = bh >> 4, h = bh & 15;
  const int bS = b * 2048;
  const int qi = 15 - blockIdx.x;          // LPT order
  const int qb = qi * 128 + w * 32;
  const int nkt = 2 * qi + 2;
  const float KSC  = 0.10206207261596577f;  // 1/sqrt(96)
  const float KOFF = 8.16496580927726f;     // 80/sqrt(96): hard bound on clipped*scaled score
  const bf16x8 kones = ones8();

  // Q fragments (from C2: Qc at h*64, roped Qr at 1024+h*32)
  bf16x8 qf[2][3];
#pragma unroll
  for (int mi = 0; mi < 2; ++mi) {
    const unsigned short* qp = C2 + (long)(bS + qb + mi * 16 + ln) * 1536;
    qf[mi][0] = *(const bf16x8*)(qp + h * 64 + quad * 8);
    qf[mi][1] = *(const bf16x8*)(qp + h * 64 + 32 + quad * 8);
    qf[mi][2] = *(const bf16x8*)(qp + 1024 + h * 32 + quad * 8);
  }

  f32x4 zero = {0.f, 0.f, 0.f, 0.f};
  f32x4 o[2][4], lacc[2];
#pragma unroll
  for (int mi = 0; mi < 2; ++mi) {
    lacc[mi] = zero;
#pragma unroll
    for (int nb = 0; nb < 4; ++nb) o[mi][nb] = zero;
  }

  // Cooperative staging (K and V only). Swizzle: chunk slot c holds source chunk c^(r&7).
  auto stage = [&](int buf, int key0) {
#pragma unroll
    for (int t = w; t < 8; t += 4) {   // Kc: 64 rows x 128B (C3 ld=1024 now)
      int ci = t * 64 + lane;
      int r = ci >> 3, c = (ci & 7) ^ (r & 7);
      load_lds16(C3 + (size_t)(bS + key0 + r) * 1024 + h * 64 + c * 8, &Ks[buf][t * 512]);
    }
#pragma unroll
    for (int t = w; t < 8; t += 4) {   // V^T: 64 d-rows x 128B
      int ci = t * 64 + lane;
      int r = ci >> 3, c = (ci & 7) ^ (r & 7);
      load_lds16(Vt + (size_t)((size_t)bh * 64 + r) * 2048 + key0 + c * 8, &Vs[buf][t * 512]);
    }
  };

  stage(0, 0);
  for (int kt = 0; kt < nkt; ++kt) {
    __syncthreads();                    // drains vmcnt(0): stage(kt) visible to all
    const int c0 = kt * 64;
    const bool live = (c0 <= qb + 31);
    // Kr fragments from global, BEFORE next stage (FIFO vmcnt: waiting on these
    // does not force the stage DMAs to complete).
    bf16x8 kr[4];
    if (live) {
#pragma unroll
      for (int ni = 0; ni < 4; ++ni)
        kr[ni] = *(const bf16x8*)(Krr + (size_t)(bS + c0 + ni * 16 + ln) * 32 + quad * 8);
    }
    if (kt + 1 < nkt) stage((kt + 1) & 1, (kt + 1) * 64);
    if (!live) continue;                // fully-masked tile for this wave: barriers only

    const unsigned short* Kp = Ks[kt & 1];
    const unsigned short* Vp = Vs[kt & 1];

    f32x4 s0[4], s1[4];
#pragma unroll
    for (int ni = 0; ni < 4; ++ni) { s0[ni] = zero; s1[ni] = zero; }
#pragma unroll
    for (int ni = 0; ni < 4; ++ni) {
      int key = ni * 16 + ln;
      bf16x8 kf0 = *(const bf16x8*)(Kp + key * 64 + ((quad ^ (key & 7)) * 8));
      bf16x8 kf1 = *(const bf16x8*)(Kp + key * 64 + (((4 | quad) ^ (key & 7)) * 8));
      s0[ni] = mfma16(qf[0][0], kf0, s0[ni]);
      s0[ni] = mfma16(qf[0][1], kf1, s0[ni]);
      s0[ni] = mfma16(qf[0][2], kr[ni], s0[ni]);
      s1[ni] = mfma16(qf[1][0], kf0, s1[ni]);
      s1[ni] = mfma16(qf[1][1], kf1, s1[ni]);
      s1[ni] = mfma16(qf[1][2], kr[ni], s1[ni]);
    }
    bf16x8 vf[4][2];
#pragma unroll
    for (int nb = 0; nb < 4; ++nb) {
      int d = nb * 16 + ln;
#pragma unroll
      for (int ks = 0; ks < 2; ++ks)
        vf[nb][ks] = *(const bf16x8*)(Vp + d * 64 + (((ks * 4 + quad) ^ (d & 7)) * 8));
    }

#pragma unroll
    for (int mi = 0; mi < 2; ++mi) {
      f32x4* sp = mi ? s1 : s0;
      const bool nm = (c0 + 63) > (qb + mi * 16);  // tile touches the diagonal
      unsigned short* P = Ps[w];
#pragma unroll
      for (int ni = 0; ni < 4; ++ni)
#pragma unroll
        for (int r = 0; r < 4; ++r) {
          float t = fminf(fmaxf(sp[ni][r], -80.f), 80.f);    // clip BEFORE scale (ref order)
          float z = fmaf(t, KSC, -KOFF);                     // z - M, z <= M guaranteed
          if (nm && (c0 + ni * 16 + ln) > (qb + mi * 16 + quad * 4 + r)) z = -1e30f;
          int q = quad * 4 + r;
          P[q * 64 + (((ni * 2 + (ln >> 3)) ^ (q & 7)) * 8) + (ln & 7)] = f2b(__expf(z));
        }
      LGKM_DRAIN();   // RAW: P writes visible; vmcnt (prefetch) untouched
      bf16x8 pf0 = *(const bf16x8*)(P + ln * 64 + ((quad ^ (ln & 7)) * 8));
      bf16x8 pf1 = *(const bf16x8*)(P + ln * 64 + (((4 | quad) ^ (ln & 7)) * 8));
      lacc[mi] = mfma16(pf0, kones, lacc[mi]);   // row-sum of P via MFMA
      lacc[mi] = mfma16(pf1, kones, lacc[mi]);
#pragma unroll
      for (int nb = 0; nb < 4; ++nb) {
        o[mi][nb] = mfma16(pf0, vf[nb][0], o[mi][nb]);
        o[mi][nb] = mfma16(pf1, vf[nb][1], o[mi][nb]);
      }
      // WAR on P across mi is safe: compiler's lgkm wait before the MFMAs that
      // consume pf0/pf1 guarantees the reads completed before the next writes issue.
    }
  }

  // epilogue: Oa layout (B,S,H*64) bf16; lacc same C-layout as o
#pragma unroll
  for (int mi = 0; mi < 2; ++mi) {
    float rl[4];
#pragma unroll
    for (int r = 0; r < 4; ++r) rl[r] = 1.0f / lacc[mi][r];
#pragma unroll
    for (int nb = 0; nb < 4; ++nb)
#pragma unroll
      for (int r = 0; r < 4; ++r) {
        long row = (long)(bS + qb + mi * 16 + quad * 4 + r);
        Oa[row * 1024 + h * 64 + nb * 16 + ln] = f2b(o[mi][nb][r] * rl[r]);
      }
  }
}

// ---------------- launcher ----------------
extern "C" void kernel_launch(void* const* d_in, const int* in_sizes, int n_in,
                              void* d_out, int out_size, void* d_ws, size_t ws_size,
                              hipStream_t stream) {
  (void)in_sizes; (void)n_in; (void)out_size; (void)ws_size;
  const float* x     = (const float*)d_in[0];
  const float* W_DQ  = (const float*)d_in[1];
  const float* W_UQ  = (const float*)d_in[2];
  const float* W_QR  = (const float*)d_in[3];
  const float* W_DKV = (const float*)d_in[4];
  const float* W_UK  = (const float*)d_in[5];
  const float* W_UV  = (const float*)d_in[6];
  const float* W_KR  = (const float*)d_in[7];
  const float* W_O   = (const float*)d_in[8];

  char* p = (char*)d_ws;
  unsigned short* xb  = (unsigned short*)p; p += (size_t)8192 * 1024 * 2;
  unsigned short* WT1 = (unsigned short*)p; p += (size_t)544 * 1024 * 2;   // [W_DQ^T; W_DKV^T; W_KR^T]
  unsigned short* WT2 = (unsigned short*)p; p += (size_t)1536 * 256 * 2;   // [W_UQ^T; W_QR^T]
  unsigned short* WT3 = (unsigned short*)p; p += (size_t)2048 * 256 * 2;   // [W_UK^T; W_UV^T]
  unsigned short* WT4 = (unsigned short*)p; p += (size_t)1024 * 1024 * 2;  // W_O^T
  unsigned short* C1  = (unsigned short*)p; p += (size_t)8192 * 544 * 2;   // [c_q | c_kv | kr_raw]
  unsigned short* C2  = (unsigned short*)p; p += (size_t)8192 * 1536 * 2;  // [Qc | Qr(roped in-place)]
  unsigned short* C3  = (unsigned short*)p; p += (size_t)8192 * 1024 * 2;  // Kc only
  unsigned short* Krr = (unsigned short*)p; p += (size_t)8192 * 32 * 2;    // roped Kr
  unsigned short* Vt  = (unsigned short*)p; p += (size_t)64 * 64 * 2048 * 2;
  unsigned short* Oa  = (unsigned short*)p; p += (size_t)8192 * 1024 * 2;  // attn out (B,S,1024)

  convert_x<<<8192, 256, 0, stream>>>(x, xb);

  TWArgs tw;
  tw.W[0] = W_DQ;  tw.T[0] = WT1;
  tw.W[1] = W_DKV; tw.T[1] = WT1 + 256 * 1024;
  tw.W[2] = W_KR;  tw.T[2] = WT1 + 512 * 1024;
  tw.W[3] = W_UQ;  tw.T[3] = WT2;
  tw.W[4] = W_QR;  tw.T[4] = WT2 + 1024 * 256;
  tw.W[5] = W_UK;  tw.T[5] = WT3;
  tw.W[6] = W_UV;  tw.T[6] = WT3 + 1024 * 256;
  tw.W[7] = W_O;   tw.T[7] = WT4;
  transpose_w_all<<<2464, 256, 0, stream>>>(tw);

  gemm_bt<true><<<dim3(64, 5),  256, 0, stream>>>(xb, 1024, WT1, 1024, C1, 544, 544, 1024);
  gemm_bt<true><<<dim3(64, 12), 256, 0, stream>>>(C1, 544, WT2, 256, C2, 1536, 1536, 256);
  gemm_bt<true><<<dim3(64, 8),  256, 0, stream>>>(C1 + 256, 544, WT3, 256, C3, 1024, 1024, 256);
  gemm_bt_vt<<<dim3(64, 8),     256, 0, stream>>>(C1 + 256, 544, WT3 + 1024 * 256, 256, Vt, 256);
  rope_qk<<<8704, 256, 0, stream>>>(C2, C1, Krr);
  flash_attn<<<dim3(16, 64), 256, 0, stream>>>(C2, C3, Krr, Vt, Oa);
  gemm_bt<false><<<dim3(64, 8), 256, 0, stream>>>(Oa, 1024, WT4, 1024, d_out, 1024, 1024, 1024);
}

// Round 5
// 540.145 us; speedup vs baseline: 1.4929x; 1.4929x over previous
//
#include <hip/hip_runtime.h>
#include <hip/hip_bf16.h>

// MLA forward, MI355X/gfx950.
// B=4, S=2048, D_MODEL=1024, H=16, D_H=64, D_HR=32, D_LATENT=256, d_qk=96.

typedef __attribute__((ext_vector_type(8))) __bf16 bf16x8;
typedef __attribute__((ext_vector_type(4))) float f32x4;
typedef __attribute__((ext_vector_type(4))) unsigned short us4;

#define DEV static __device__ __forceinline__

DEV unsigned short f2b(float f) {
  union { __hip_bfloat16 h; unsigned short u; } v;
  v.h = __float2bfloat16(f);
  return v.u;
}
DEV float b2f(unsigned short u) {
  union { unsigned short u; __hip_bfloat16 h; } v;
  v.u = u;
  return __bfloat162float(v.h);
}
DEV f32x4 mfma16(bf16x8 a, bf16x8 b, f32x4 c) {
  return __builtin_amdgcn_mfma_f32_16x16x32_bf16(a, b, c, 0, 0, 0);
}
DEV void load_lds16(const void* g, void* lds) {
  __builtin_amdgcn_global_load_lds((__attribute__((address_space(1))) void*)g,
                                   (__attribute__((address_space(3))) void*)lds,
                                   16, 0, 0);
}
DEV bf16x8 ones8() {
  union { unsigned short u[8]; bf16x8 v; } c;
#pragma unroll
  for (int i = 0; i < 8; ++i) c.u[i] = 0x3F80;  // bf16 1.0
  return c.v;
}
// LDS-only drain: does NOT touch vmcnt, so global_load_lds prefetch stays in flight.
#define LGKM_DRAIN() __asm__ volatile("s_waitcnt lgkmcnt(0)" ::: "memory")

// ---------------- convert x (fp32 -> bf16) ----------------
__global__ __launch_bounds__(256) void convert_x(const float* __restrict__ x,
                                                 unsigned short* __restrict__ xb) {
  long i = (long)(blockIdx.x * 256 + threadIdx.x) * 4;
  float4 v = *(const float4*)(x + i);
  us4 o = { f2b(v.x), f2b(v.y), f2b(v.z), f2b(v.w) };
  *(us4*)(xb + i) = o;
}

// ---------------- batched weight transpose: 8 weights in ONE dispatch ----------------
// W (K x N) fp32 -> WT (N x K) bf16. All K,N multiples of 32.
struct TWArgs { const float* W[8]; unsigned short* T[8]; };
__global__ __launch_bounds__(256) void transpose_w_all(TWArgs a) {
  int bid = blockIdx.x;
  // ranges: [0,256) DQ | [256,512) DKV | [512,544) KR | [544,800) UQ |
  //         [800,928) QR | [928,1184) UK | [1184,1440) UV | [1440,2464) O
  int g;
  if      (bid < 256)  g = 0;
  else if (bid < 512)  g = 1;
  else if (bid < 544)  g = 2;
  else if (bid < 800)  g = 3;
  else if (bid < 928)  g = 4;
  else if (bid < 1184) g = 5;
  else if (bid < 1440) g = 6;
  else                 g = 7;
  const int starts[8] = {0, 256, 512, 544, 800, 928, 1184, 1440};
  int local = bid - starts[g];
  int K = (g >= 3 && g <= 6) ? 256 : 1024;
  int N = (g < 2) ? 256 : (g == 2 ? 32 : (g == 4 ? 512 : 1024));
  int tilesX = N >> 5;
  int n0 = (local % tilesX) * 32, k0 = (local / tilesX) * 32;
  const float* W = a.W[g];
  unsigned short* WT = a.T[g];
  __shared__ float tile[32][33];
  int tx = threadIdx.x & 31, ty = threadIdx.x >> 5;
#pragma unroll
  for (int i = 0; i < 32; i += 8)
    tile[ty + i][tx] = W[(size_t)(k0 + ty + i) * N + n0 + tx];
  __syncthreads();
#pragma unroll
  for (int i = 0; i < 32; i += 8)
    WT[(size_t)(n0 + ty + i) * K + k0 + tx] = f2b(tile[tx][ty + i]);
}

// ---------------- fused RoPE: Qr in-place in C2, Kr C1->Krr ----------------
__global__ __launch_bounds__(256) void rope_qk(unsigned short* __restrict__ C2,
                                               const unsigned short* __restrict__ C1,
                                               unsigned short* __restrict__ Krr) {
  if (blockIdx.x < 8192) {
    int idx = blockIdx.x * 256 + threadIdx.x;   // 2^21 threads exact
    int i = idx & 15, h = (idx >> 4) & 15, s = (idx >> 8) & 2047, b = idx >> 19;
    long base = (long)(b * 2048 + s) * 1536 + 1024 + h * 32 + 2 * i;
    float x1 = b2f(C2[base]), x2 = b2f(C2[base + 1]);
    float inv = exp2f(-(float)i * 0.8304820237686285f);  // 10000^(-i/16)
    float ang = (float)s * inv;
    float c = cosf(ang), sn = sinf(ang);
    C2[base]     = f2b(x1 * c - x2 * sn);
    C2[base + 1] = f2b(x1 * sn + x2 * c);
  } else {
    int idx = (blockIdx.x - 8192) * 256 + threadIdx.x;   // 2^17 threads exact
    int i = idx & 15, s = (idx >> 4) & 2047, b = idx >> 15;
    long src = (long)(b * 2048 + s) * 544 + 512 + 2 * i;
    float x1 = b2f(C1[src]), x2 = b2f(C1[src + 1]);
    float inv = exp2f(-(float)i * 0.8304820237686285f);
    float ang = (float)s * inv;
    float c = cosf(ang), sn = sinf(ang);
    long dst = (long)(b * 2048 + s) * 32 + 2 * i;
    Krr[dst]     = f2b(x1 * c - x2 * sn);
    Krr[dst + 1] = f2b(x1 * sn + x2 * c);
  }
}

// ---------------- GEMM: C(M x N) = A(M x K, lda) @ Bt(N x K, ldb)^T ----------------
template <bool OUT_BF16>
__global__ __launch_bounds__(256) void gemm_bt(const unsigned short* __restrict__ A, int lda,
                                               const unsigned short* __restrict__ Bt, int ldb,
                                               void* __restrict__ Cv, int ldc, int N, int K) {
  __shared__ __align__(16) unsigned short As[128 * 32];
  __shared__ __align__(16) unsigned short Bs[128 * 32];
  const int t = threadIdx.x;
  const int w = t >> 6, lane = t & 63, ln = lane & 15, quad = lane >> 4;
  const int wr = w >> 1, wc = w & 1;
  const int bm0 = blockIdx.x * 128, bn0 = blockIdx.y * 128;
  const int srow = t >> 2;          // 0..63
  const int scol = (t & 3) * 8;     // 0,8,16,24
  f32x4 zero = {0.f, 0.f, 0.f, 0.f};
  f32x4 acc[4][4];
#pragma unroll
  for (int i = 0; i < 4; ++i)
#pragma unroll
    for (int j = 0; j < 4; ++j) acc[i][j] = zero;

  for (int k0 = 0; k0 < K; k0 += 32) {
#pragma unroll
    for (int r = 0; r < 2; ++r) {
      int arow = bm0 + r * 64 + srow;
      load_lds16(A + (long)arow * lda + k0 + scol, (char*)As + r * 4096 + w * 1024);
      int brow = bn0 + r * 64 + srow;
      if (brow > N - 1) brow = N - 1;  // clamp (garbage cols guarded at write)
      load_lds16(Bt + (long)brow * ldb + k0 + scol, (char*)Bs + r * 4096 + w * 1024);
    }
    __syncthreads();
    bf16x8 af[4], bf[4];
#pragma unroll
    for (int i = 0; i < 4; ++i)
      af[i] = *(const bf16x8*)(As + (wr * 64 + i * 16 + ln) * 32 + quad * 8);
#pragma unroll
    for (int j = 0; j < 4; ++j)
      bf[j] = *(const bf16x8*)(Bs + (wc * 64 + j * 16 + ln) * 32 + quad * 8);
#pragma unroll
    for (int i = 0; i < 4; ++i)
#pragma unroll
      for (int j = 0; j < 4; ++j) acc[i][j] = mfma16(af[i], bf[j], acc[i][j]);
    __syncthreads();
  }
#pragma unroll
  for (int i = 0; i < 4; ++i)
#pragma unroll
    for (int j = 0; j < 4; ++j)
#pragma unroll
      for (int r = 0; r < 4; ++r) {
        int row = bm0 + wr * 64 + i * 16 + quad * 4 + r;
        int col = bn0 + wc * 64 + j * 16 + ln;
        if (col < N) {
          if (OUT_BF16)
            ((unsigned short*)Cv)[(long)row * ldc + col] = f2b(acc[i][j][r]);
          else
            ((float*)Cv)[(long)row * ldc + col] = acc[i][j][r];
        }
      }
}

// ---------------- V GEMM with transposed epilogue: writes Vt[bh*64+d][s] directly ----------------
// A = c_kv (M x 256), Bt = W_UV^T (1024 x 256). N=1024 fixed. Kills transpose_v.
__global__ __launch_bounds__(256) void gemm_bt_vt(const unsigned short* __restrict__ A, int lda,
                                                  const unsigned short* __restrict__ Bt, int ldb,
                                                  unsigned short* __restrict__ Vt, int K) {
  __shared__ __align__(16) unsigned short As[128 * 32];
  __shared__ __align__(16) unsigned short Bs[128 * 32];
  const int t = threadIdx.x;
  const int w = t >> 6, lane = t & 63, ln = lane & 15, quad = lane >> 4;
  const int wr = w >> 1, wc = w & 1;
  const int bm0 = blockIdx.x * 128, bn0 = blockIdx.y * 128;
  const int srow = t >> 2, scol = (t & 3) * 8;
  f32x4 zero = {0.f, 0.f, 0.f, 0.f};
  f32x4 acc[4][4];
#pragma unroll
  for (int i = 0; i < 4; ++i)
#pragma unroll
    for (int j = 0; j < 4; ++j) acc[i][j] = zero;

  for (int k0 = 0; k0 < K; k0 += 32) {
#pragma unroll
    for (int r = 0; r < 2; ++r) {
      load_lds16(A + (long)(bm0 + r * 64 + srow) * lda + k0 + scol, (char*)As + r * 4096 + w * 1024);
      load_lds16(Bt + (long)(bn0 + r * 64 + srow) * ldb + k0 + scol, (char*)Bs + r * 4096 + w * 1024);
    }
    __syncthreads();
    bf16x8 af[4], bf[4];
#pragma unroll
    for (int i = 0; i < 4; ++i)
      af[i] = *(const bf16x8*)(As + (wr * 64 + i * 16 + ln) * 32 + quad * 8);
#pragma unroll
    for (int j = 0; j < 4; ++j)
      bf[j] = *(const bf16x8*)(Bs + (wc * 64 + j * 16 + ln) * 32 + quad * 8);
#pragma unroll
    for (int i = 0; i < 4; ++i)
#pragma unroll
      for (int j = 0; j < 4; ++j) acc[i][j] = mfma16(af[i], bf[j], acc[i][j]);
    __syncthreads();
  }
  // transposed epilogue: col = h*64+d; rows r=0..3 consecutive -> one 8B store per (i,j)
#pragma unroll
  for (int i = 0; i < 4; ++i)
#pragma unroll
    for (int j = 0; j < 4; ++j) {
      int col = bn0 + wc * 64 + j * 16 + ln;          // 0..1023 = h*64+d
      int row0 = bm0 + wr * 64 + i * 16 + quad * 4;   // 4 consecutive seq rows, same b
      int b = row0 >> 11, sl = row0 & 2047;
      us4 pk = { f2b(acc[i][j][0]), f2b(acc[i][j][1]), f2b(acc[i][j][2]), f2b(acc[i][j][3]) };
      *(us4*)(Vt + ((size_t)(b * 16) * 64 + col) * 2048 + sl) = pk;  // (b*16+h)*64+d == b*1024+col
    }
}

// ---------------- Flash attention v3b ----------------
// grid (16, 64), qi = 15-x (LPT). 40KB LDS.
// __launch_bounds__(256, 3): cap ~170 regs/wave. R4's (256,4) capped at 128 and
// SPILLED (VGPR 64, WRITE_SIZE 791MB of scratch traffic, 618us). The kernel's
// natural working set is ~130-160 regs; 3 waves/EU is the right floor.
__global__ __launch_bounds__(256, 3) void flash_attn(const unsigned short* __restrict__ C2,
                                                     const unsigned short* __restrict__ C3,
                                                     const unsigned short* __restrict__ Krr,
                                                     const unsigned short* __restrict__ Vt,
                                                     unsigned short* __restrict__ Oa) {
  __shared__ __align__(16) unsigned short Ks[2][4096];   // 64 keys x 64 dims (swizzled 16B chunks)
  __shared__ __align__(16) unsigned short Vs[2][4096];   // 64 d    x 64 keys
  __shared__ __align__(16) unsigned short Ps[4][1024];   // per-wave P: 16 q x 64 keys

  const int tid = threadIdx.x;
  const int w = tid >> 6, lane = tid & 63, ln = lane & 15, quad = lane >> 4;
  const int bh = blockIdx.y, b = bh >> 4, h = bh & 15;
  const int bS = b * 2048;
  const int qi = 15 - blockIdx.x;          // LPT order
  const int qb = qi * 128 + w * 32;
  const int nkt = 2 * qi + 2;
  const float KSC  = 0.10206207261596577f;  // 1/sqrt(96)
  const float KOFF = 8.16496580927726f;     // 80/sqrt(96): hard bound on clipped*scaled score
  const bf16x8 kones = ones8();

  // Q fragments (from C2: Qc at h*64, roped Qr at 1024+h*32)
  bf16x8 qf[2][3];
#pragma unroll
  for (int mi = 0; mi < 2; ++mi) {
    const unsigned short* qp = C2 + (long)(bS + qb + mi * 16 + ln) * 1536;
    qf[mi][0] = *(const bf16x8*)(qp + h * 64 + quad * 8);
    qf[mi][1] = *(const bf16x8*)(qp + h * 64 + 32 + quad * 8);
    qf[mi][2] = *(const bf16x8*)(qp + 1024 + h * 32 + quad * 8);
  }

  f32x4 zero = {0.f, 0.f, 0.f, 0.f};
  f32x4 o[2][4], lacc[2];
#pragma unroll
  for (int mi = 0; mi < 2; ++mi) {
    lacc[mi] = zero;
#pragma unroll
    for (int nb = 0; nb < 4; ++nb) o[mi][nb] = zero;
  }

  // Cooperative staging (K and V only). Swizzle: chunk slot c holds source chunk c^(r&7).
  auto stage = [&](int buf, int key0) {
#pragma unroll
    for (int t = w; t < 8; t += 4) {   // Kc: 64 rows x 128B (C3 ld=1024 now)
      int ci = t * 64 + lane;
      int r = ci >> 3, c = (ci & 7) ^ (r & 7);
      load_lds16(C3 + (size_t)(bS + key0 + r) * 1024 + h * 64 + c * 8, &Ks[buf][t * 512]);
    }
#pragma unroll
    for (int t = w; t < 8; t += 4) {   // V^T: 64 d-rows x 128B
      int ci = t * 64 + lane;
      int r = ci >> 3, c = (ci & 7) ^ (r & 7);
      load_lds16(Vt + (size_t)((size_t)bh * 64 + r) * 2048 + key0 + c * 8, &Vs[buf][t * 512]);
    }
  };

  stage(0, 0);
  for (int kt = 0; kt < nkt; ++kt) {
    __syncthreads();                    // drains vmcnt(0): stage(kt) visible to all
    const int c0 = kt * 64;
    const bool live = (c0 <= qb + 31);
    // Kr fragments from global, BEFORE next stage (FIFO vmcnt: waiting on these
    // does not force the stage DMAs to complete).
    bf16x8 kr[4];
    if (live) {
#pragma unroll
      for (int ni = 0; ni < 4; ++ni)
        kr[ni] = *(const bf16x8*)(Krr + (size_t)(bS + c0 + ni * 16 + ln) * 32 + quad * 8);
    }
    if (kt + 1 < nkt) stage((kt + 1) & 1, (kt + 1) * 64);
    if (!live) continue;                // fully-masked tile for this wave: barriers only

    const unsigned short* Kp = Ks[kt & 1];
    const unsigned short* Vp = Vs[kt & 1];

    f32x4 s0[4], s1[4];
#pragma unroll
    for (int ni = 0; ni < 4; ++ni) { s0[ni] = zero; s1[ni] = zero; }
#pragma unroll
    for (int ni = 0; ni < 4; ++ni) {
      int key = ni * 16 + ln;
      bf16x8 kf0 = *(const bf16x8*)(Kp + key * 64 + ((quad ^ (key & 7)) * 8));
      bf16x8 kf1 = *(const bf16x8*)(Kp + key * 64 + (((4 | quad) ^ (key & 7)) * 8));
      s0[ni] = mfma16(qf[0][0], kf0, s0[ni]);
      s0[ni] = mfma16(qf[0][1], kf1, s0[ni]);
      s0[ni] = mfma16(qf[0][2], kr[ni], s0[ni]);
      s1[ni] = mfma16(qf[1][0], kf0, s1[ni]);
      s1[ni] = mfma16(qf[1][1], kf1, s1[ni]);
      s1[ni] = mfma16(qf[1][2], kr[ni], s1[ni]);
    }
    bf16x8 vf[4][2];
#pragma unroll
    for (int nb = 0; nb < 4; ++nb) {
      int d = nb * 16 + ln;
#pragma unroll
      for (int ks = 0; ks < 2; ++ks)
        vf[nb][ks] = *(const bf16x8*)(Vp + d * 64 + (((ks * 4 + quad) ^ (d & 7)) * 8));
    }

#pragma unroll
    for (int mi = 0; mi < 2; ++mi) {
      f32x4* sp = mi ? s1 : s0;
      const bool nm = (c0 + 63) > (qb + mi * 16);  // tile touches the diagonal
      unsigned short* P = Ps[w];
#pragma unroll
      for (int ni = 0; ni < 4; ++ni)
#pragma unroll
        for (int r = 0; r < 4; ++r) {
          float t = fminf(fmaxf(sp[ni][r], -80.f), 80.f);    // clip BEFORE scale (ref order)
          float z = fmaf(t, KSC, -KOFF);                     // z - M, z <= M guaranteed
          if (nm && (c0 + ni * 16 + ln) > (qb + mi * 16 + quad * 4 + r)) z = -1e30f;
          int q = quad * 4 + r;
          P[q * 64 + (((ni * 2 + (ln >> 3)) ^ (q & 7)) * 8) + (ln & 7)] = f2b(__expf(z));
        }
      LGKM_DRAIN();   // RAW: P writes visible; vmcnt (prefetch) untouched
      bf16x8 pf0 = *(const bf16x8*)(P + ln * 64 + ((quad ^ (ln & 7)) * 8));
      bf16x8 pf1 = *(const bf16x8*)(P + ln * 64 + (((4 | quad) ^ (ln & 7)) * 8));
      lacc[mi] = mfma16(pf0, kones, lacc[mi]);   // row-sum of P via MFMA
      lacc[mi] = mfma16(pf1, kones, lacc[mi]);
#pragma unroll
      for (int nb = 0; nb < 4; ++nb) {
        o[mi][nb] = mfma16(pf0, vf[nb][0], o[mi][nb]);
        o[mi][nb] = mfma16(pf1, vf[nb][1], o[mi][nb]);
      }
      // WAR on P across mi is safe: compiler's lgkm wait before the MFMAs that
      // consume pf0/pf1 guarantees the reads completed before the next writes issue.
    }
  }

  // epilogue: Oa layout (B,S,H*64) bf16; lacc same C-layout as o
#pragma unroll
  for (int mi = 0; mi < 2; ++mi) {
    float rl[4];
#pragma unroll
    for (int r = 0; r < 4; ++r) rl[r] = 1.0f / lacc[mi][r];
#pragma unroll
    for (int nb = 0; nb < 4; ++nb)
#pragma unroll
      for (int r = 0; r < 4; ++r) {
        long row = (long)(bS + qb + mi * 16 + quad * 4 + r);
        Oa[row * 1024 + h * 64 + nb * 16 + ln] = f2b(o[mi][nb][r] * rl[r]);
      }
  }
}

// ---------------- launcher ----------------
extern "C" void kernel_launch(void* const* d_in, const int* in_sizes, int n_in,
                              void* d_out, int out_size, void* d_ws, size_t ws_size,
                              hipStream_t stream) {
  (void)in_sizes; (void)n_in; (void)out_size; (void)ws_size;
  const float* x     = (const float*)d_in[0];
  const float* W_DQ  = (const float*)d_in[1];
  const float* W_UQ  = (const float*)d_in[2];
  const float* W_QR  = (const float*)d_in[3];
  const float* W_DKV = (const float*)d_in[4];
  const float* W_UK  = (const float*)d_in[5];
  const float* W_UV  = (const float*)d_in[6];
  const float* W_KR  = (const float*)d_in[7];
  const float* W_O   = (const float*)d_in[8];

  char* p = (char*)d_ws;
  unsigned short* xb  = (unsigned short*)p; p += (size_t)8192 * 1024 * 2;
  unsigned short* WT1 = (unsigned short*)p; p += (size_t)544 * 1024 * 2;   // [W_DQ^T; W_DKV^T; W_KR^T]
  unsigned short* WT2 = (unsigned short*)p; p += (size_t)1536 * 256 * 2;   // [W_UQ^T; W_QR^T]
  unsigned short* WT3 = (unsigned short*)p; p += (size_t)2048 * 256 * 2;   // [W_UK^T; W_UV^T]
  unsigned short* WT4 = (unsigned short*)p; p += (size_t)1024 * 1024 * 2;  // W_O^T
  unsigned short* C1  = (unsigned short*)p; p += (size_t)8192 * 544 * 2;   // [c_q | c_kv | kr_raw]
  unsigned short* C2  = (unsigned short*)p; p += (size_t)8192 * 1536 * 2;  // [Qc | Qr(roped in-place)]
  unsigned short* C3  = (unsigned short*)p; p += (size_t)8192 * 1024 * 2;  // Kc only
  unsigned short* Krr = (unsigned short*)p; p += (size_t)8192 * 32 * 2;    // roped Kr
  unsigned short* Vt  = (unsigned short*)p; p += (size_t)64 * 64 * 2048 * 2;
  unsigned short* Oa  = (unsigned short*)p; p += (size_t)8192 * 1024 * 2;  // attn out (B,S,1024)

  convert_x<<<8192, 256, 0, stream>>>(x, xb);

  TWArgs tw;
  tw.W[0] = W_DQ;  tw.T[0] = WT1;
  tw.W[1] = W_DKV; tw.T[1] = WT1 + 256 * 1024;
  tw.W[2] = W_KR;  tw.T[2] = WT1 + 512 * 1024;
  tw.W[3] = W_UQ;  tw.T[3] = WT2;
  tw.W[4] = W_QR;  tw.T[4] = WT2 + 1024 * 256;
  tw.W[5] = W_UK;  tw.T[5] = WT3;
  tw.W[6] = W_UV;  tw.T[6] = WT3 + 1024 * 256;
  tw.W[7] = W_O;   tw.T[7] = WT4;
  transpose_w_all<<<2464, 256, 0, stream>>>(tw);

  gemm_bt<true><<<dim3(64, 5),  256, 0, stream>>>(xb, 1024, WT1, 1024, C1, 544, 544, 1024);
  gemm_bt<true><<<dim3(64, 12), 256, 0, stream>>>(C1, 544, WT2, 256, C2, 1536, 1536, 256);
  gemm_bt<true><<<dim3(64, 8),  256, 0, stream>>>(C1 + 256, 544, WT3, 256, C3, 1024, 1024, 256);
  gemm_bt_vt<<<dim3(64, 8),     256, 0, stream>>>(C1 + 256, 544, WT3 + 1024 * 256, 256, Vt, 256);
  rope_qk<<<8704, 256, 0, stream>>>(C2, C1, Krr);
  flash_attn<<<dim3(16, 64), 256, 0, stream>>>(C2, C3, Krr, Vt, Oa);
  gemm_bt<false><<<dim3(64, 8), 256, 0, stream>>>(Oa, 1024, WT4, 1024, d_out, 1024, 1024, 1024);
}

// Round 6
// 379.787 us; speedup vs baseline: 2.1233x; 1.4222x over previous
//
#include <hip/hip_runtime.h>
#include <hip/hip_bf16.h>

// MLA forward, MI355X/gfx950.
// B=4, S=2048, D_MODEL=1024, H=16, D_H=64, D_HR=32, D_LATENT=256, d_qk=96.

typedef __attribute__((ext_vector_type(8))) __bf16 bf16x8;
typedef __attribute__((ext_vector_type(4))) float f32x4;
typedef __attribute__((ext_vector_type(4))) unsigned short us4;

#define DEV static __device__ __forceinline__

DEV unsigned short f2b(float f) {
  union { __hip_bfloat16 h; unsigned short u; } v;
  v.h = __float2bfloat16(f);
  return v.u;
}
DEV float b2f(unsigned short u) {
  union { unsigned short u; __hip_bfloat16 h; } v;
  v.u = u;
  return __bfloat162float(v.h);
}
DEV f32x4 mfma16(bf16x8 a, bf16x8 b, f32x4 c) {
  return __builtin_amdgcn_mfma_f32_16x16x32_bf16(a, b, c, 0, 0, 0);
}
DEV void load_lds16(const void* g, void* lds) {
  __builtin_amdgcn_global_load_lds((__attribute__((address_space(1))) void*)g,
                                   (__attribute__((address_space(3))) void*)lds,
                                   16, 0, 0);
}
DEV bf16x8 ones8() {
  union { unsigned short u[8]; bf16x8 v; } c;
#pragma unroll
  for (int i = 0; i < 8; ++i) c.u[i] = 0x3F80;  // bf16 1.0
  return c.v;
}
// LDS-only drain: does NOT touch vmcnt, so global_load_lds prefetch stays in flight.
#define LGKM_DRAIN() __asm__ volatile("s_waitcnt lgkmcnt(0)" ::: "memory")

// ---------------- convert x (fp32 -> bf16) ----------------
__global__ __launch_bounds__(256) void convert_x(const float* __restrict__ x,
                                                 unsigned short* __restrict__ xb) {
  long i = (long)(blockIdx.x * 256 + threadIdx.x) * 4;
  float4 v = *(const float4*)(x + i);
  us4 o = { f2b(v.x), f2b(v.y), f2b(v.z), f2b(v.w) };
  *(us4*)(xb + i) = o;
}

// ---------------- batched weight transpose: 8 weights in ONE dispatch ----------------
// W (K x N) fp32 -> WT (N x K) bf16. All K,N multiples of 32.
struct TWArgs { const float* W[8]; unsigned short* T[8]; };
__global__ __launch_bounds__(256) void transpose_w_all(TWArgs a) {
  int bid = blockIdx.x;
  int g;
  if      (bid < 256)  g = 0;
  else if (bid < 512)  g = 1;
  else if (bid < 544)  g = 2;
  else if (bid < 800)  g = 3;
  else if (bid < 928)  g = 4;
  else if (bid < 1184) g = 5;
  else if (bid < 1440) g = 6;
  else                 g = 7;
  const int starts[8] = {0, 256, 512, 544, 800, 928, 1184, 1440};
  int local = bid - starts[g];
  int K = (g >= 3 && g <= 6) ? 256 : 1024;
  int N = (g < 2) ? 256 : (g == 2 ? 32 : (g == 4 ? 512 : 1024));
  int tilesX = N >> 5;
  int n0 = (local % tilesX) * 32, k0 = (local / tilesX) * 32;
  const float* W = a.W[g];
  unsigned short* WT = a.T[g];
  __shared__ float tile[32][33];
  int tx = threadIdx.x & 31, ty = threadIdx.x >> 5;
#pragma unroll
  for (int i = 0; i < 32; i += 8)
    tile[ty + i][tx] = W[(size_t)(k0 + ty + i) * N + n0 + tx];
  __syncthreads();
#pragma unroll
  for (int i = 0; i < 32; i += 8)
    WT[(size_t)(n0 + ty + i) * K + k0 + tx] = f2b(tile[tx][ty + i]);
}

// ---------------- fused RoPE: Qr in-place in C2, Kr C1->Krr ----------------
__global__ __launch_bounds__(256) void rope_qk(unsigned short* __restrict__ C2,
                                               const unsigned short* __restrict__ C1,
                                               unsigned short* __restrict__ Krr) {
  if (blockIdx.x < 8192) {
    int idx = blockIdx.x * 256 + threadIdx.x;   // 2^21 threads exact
    int i = idx & 15, h = (idx >> 4) & 15, s = (idx >> 8) & 2047, b = idx >> 19;
    long base = (long)(b * 2048 + s) * 1536 + 1024 + h * 32 + 2 * i;
    float x1 = b2f(C2[base]), x2 = b2f(C2[base + 1]);
    float inv = exp2f(-(float)i * 0.8304820237686285f);  // 10000^(-i/16)
    float ang = (float)s * inv;
    float c = cosf(ang), sn = sinf(ang);
    C2[base]     = f2b(x1 * c - x2 * sn);
    C2[base + 1] = f2b(x1 * sn + x2 * c);
  } else {
    int idx = (blockIdx.x - 8192) * 256 + threadIdx.x;   // 2^17 threads exact
    int i = idx & 15, s = (idx >> 4) & 2047, b = idx >> 15;
    long src = (long)(b * 2048 + s) * 544 + 512 + 2 * i;
    float x1 = b2f(C1[src]), x2 = b2f(C1[src + 1]);
    float inv = exp2f(-(float)i * 0.8304820237686285f);
    float ang = (float)s * inv;
    float c = cosf(ang), sn = sinf(ang);
    long dst = (long)(b * 2048 + s) * 32 + 2 * i;
    Krr[dst]     = f2b(x1 * c - x2 * sn);
    Krr[dst + 1] = f2b(x1 * sn + x2 * c);
  }
}

// ---------------- GEMM: C(M x N) = A(M x K, lda) @ Bt(N x K, ldb)^T ----------------
template <bool OUT_BF16>
__global__ __launch_bounds__(256) void gemm_bt(const unsigned short* __restrict__ A, int lda,
                                               const unsigned short* __restrict__ Bt, int ldb,
                                               void* __restrict__ Cv, int ldc, int N, int K) {
  __shared__ __align__(16) unsigned short As[128 * 32];
  __shared__ __align__(16) unsigned short Bs[128 * 32];
  const int t = threadIdx.x;
  const int w = t >> 6, lane = t & 63, ln = lane & 15, quad = lane >> 4;
  const int wr = w >> 1, wc = w & 1;
  const int bm0 = blockIdx.x * 128, bn0 = blockIdx.y * 128;
  const int srow = t >> 2;          // 0..63
  const int scol = (t & 3) * 8;     // 0,8,16,24
  f32x4 zero = {0.f, 0.f, 0.f, 0.f};
  f32x4 acc[4][4];
#pragma unroll
  for (int i = 0; i < 4; ++i)
#pragma unroll
    for (int j = 0; j < 4; ++j) acc[i][j] = zero;

  for (int k0 = 0; k0 < K; k0 += 32) {
#pragma unroll
    for (int r = 0; r < 2; ++r) {
      int arow = bm0 + r * 64 + srow;
      load_lds16(A + (long)arow * lda + k0 + scol, (char*)As + r * 4096 + w * 1024);
      int brow = bn0 + r * 64 + srow;
      if (brow > N - 1) brow = N - 1;  // clamp (garbage cols guarded at write)
      load_lds16(Bt + (long)brow * ldb + k0 + scol, (char*)Bs + r * 4096 + w * 1024);
    }
    __syncthreads();
    bf16x8 af[4], bf[4];
#pragma unroll
    for (int i = 0; i < 4; ++i)
      af[i] = *(const bf16x8*)(As + (wr * 64 + i * 16 + ln) * 32 + quad * 8);
#pragma unroll
    for (int j = 0; j < 4; ++j)
      bf[j] = *(const bf16x8*)(Bs + (wc * 64 + j * 16 + ln) * 32 + quad * 8);
#pragma unroll
    for (int i = 0; i < 4; ++i)
#pragma unroll
      for (int j = 0; j < 4; ++j) acc[i][j] = mfma16(af[i], bf[j], acc[i][j]);
    __syncthreads();
  }
#pragma unroll
  for (int i = 0; i < 4; ++i)
#pragma unroll
    for (int j = 0; j < 4; ++j)
#pragma unroll
      for (int r = 0; r < 4; ++r) {
        int row = bm0 + wr * 64 + i * 16 + quad * 4 + r;
        int col = bn0 + wc * 64 + j * 16 + ln;
        if (col < N) {
          if (OUT_BF16)
            ((unsigned short*)Cv)[(long)row * ldc + col] = f2b(acc[i][j][r]);
          else
            ((float*)Cv)[(long)row * ldc + col] = acc[i][j][r];
        }
      }
}

// ---------------- V GEMM with transposed epilogue: writes Vt[bh*64+d][s] directly ----------------
__global__ __launch_bounds__(256) void gemm_bt_vt(const unsigned short* __restrict__ A, int lda,
                                                  const unsigned short* __restrict__ Bt, int ldb,
                                                  unsigned short* __restrict__ Vt, int K) {
  __shared__ __align__(16) unsigned short As[128 * 32];
  __shared__ __align__(16) unsigned short Bs[128 * 32];
  const int t = threadIdx.x;
  const int w = t >> 6, lane = t & 63, ln = lane & 15, quad = lane >> 4;
  const int wr = w >> 1, wc = w & 1;
  const int bm0 = blockIdx.x * 128, bn0 = blockIdx.y * 128;
  const int srow = t >> 2, scol = (t & 3) * 8;
  f32x4 zero = {0.f, 0.f, 0.f, 0.f};
  f32x4 acc[4][4];
#pragma unroll
  for (int i = 0; i < 4; ++i)
#pragma unroll
    for (int j = 0; j < 4; ++j) acc[i][j] = zero;

  for (int k0 = 0; k0 < K; k0 += 32) {
#pragma unroll
    for (int r = 0; r < 2; ++r) {
      load_lds16(A + (long)(bm0 + r * 64 + srow) * lda + k0 + scol, (char*)As + r * 4096 + w * 1024);
      load_lds16(Bt + (long)(bn0 + r * 64 + srow) * ldb + k0 + scol, (char*)Bs + r * 4096 + w * 1024);
    }
    __syncthreads();
    bf16x8 af[4], bf[4];
#pragma unroll
    for (int i = 0; i < 4; ++i)
      af[i] = *(const bf16x8*)(As + (wr * 64 + i * 16 + ln) * 32 + quad * 8);
#pragma unroll
    for (int j = 0; j < 4; ++j)
      bf[j] = *(const bf16x8*)(Bs + (wc * 64 + j * 16 + ln) * 32 + quad * 8);
#pragma unroll
    for (int i = 0; i < 4; ++i)
#pragma unroll
      for (int j = 0; j < 4; ++j) acc[i][j] = mfma16(af[i], bf[j], acc[i][j]);
    __syncthreads();
  }
#pragma unroll
  for (int i = 0; i < 4; ++i)
#pragma unroll
    for (int j = 0; j < 4; ++j) {
      int col = bn0 + wc * 64 + j * 16 + ln;          // 0..1023 = h*64+d
      int row0 = bm0 + wr * 64 + i * 16 + quad * 4;   // 4 consecutive seq rows, same b
      int b = row0 >> 11, sl = row0 & 2047;
      us4 pk = { f2b(acc[i][j][0]), f2b(acc[i][j][1]), f2b(acc[i][j][2]), f2b(acc[i][j][3]) };
      *(us4*)(Vt + ((size_t)(b * 16) * 64 + col) * 2048 + sl) = pk;
    }
}

// ---------------- Flash attention v4 ----------------
// grid (16, 64), qi = 15-x (LPT). 40KB LDS, (256,3).
// Register-diet restructure vs R5 (which spilled ~150MB scratch at VGPR split 84/84):
//  - QK computed PER m-tile (s: 32->16 regs; kf are short-lived temps)
//  - V fragments loaded inside the PV loop (frees 32 regs held across tile)
// Hot-loop live set ~130 regs total -> fits the (256,3) budget of ~168, no spill.
__global__ __launch_bounds__(256, 3) void flash_attn(const unsigned short* __restrict__ C2,
                                                     const unsigned short* __restrict__ C3,
                                                     const unsigned short* __restrict__ Krr,
                                                     const unsigned short* __restrict__ Vt,
                                                     unsigned short* __restrict__ Oa) {
  __shared__ __align__(16) unsigned short Ks[2][4096];   // 64 keys x 64 dims (swizzled 16B chunks)
  __shared__ __align__(16) unsigned short Vs[2][4096];   // 64 d    x 64 keys
  __shared__ __align__(16) unsigned short Ps[4][1024];   // per-wave P: 16 q x 64 keys

  const int tid = threadIdx.x;
  const int w = tid >> 6, lane = tid & 63, ln = lane & 15, quad = lane >> 4;
  const int bh = blockIdx.y, b = bh >> 4, h = bh & 15;
  const int bS = b * 2048;
  const int qi = 15 - blockIdx.x;          // LPT order
  const int qb = qi * 128 + w * 32;
  const int nkt = 2 * qi + 2;
  const float KSC  = 0.10206207261596577f;  // 1/sqrt(96)
  const float KOFF = 8.16496580927726f;     // 80/sqrt(96): hard bound on clipped*scaled score
  const bf16x8 kones = ones8();

  bf16x8 qf[2][3];
#pragma unroll
  for (int mi = 0; mi < 2; ++mi) {
    const unsigned short* qp = C2 + (long)(bS + qb + mi * 16 + ln) * 1536;
    qf[mi][0] = *(const bf16x8*)(qp + h * 64 + quad * 8);
    qf[mi][1] = *(const bf16x8*)(qp + h * 64 + 32 + quad * 8);
    qf[mi][2] = *(const bf16x8*)(qp + 1024 + h * 32 + quad * 8);
  }

  f32x4 zero = {0.f, 0.f, 0.f, 0.f};
  f32x4 o[2][4], lacc[2];
#pragma unroll
  for (int mi = 0; mi < 2; ++mi) {
    lacc[mi] = zero;
#pragma unroll
    for (int nb = 0; nb < 4; ++nb) o[mi][nb] = zero;
  }

  auto stage = [&](int buf, int key0) {
#pragma unroll
    for (int t = w; t < 8; t += 4) {   // Kc: 64 rows x 128B (C3 ld=1024)
      int ci = t * 64 + lane;
      int r = ci >> 3, c = (ci & 7) ^ (r & 7);
      load_lds16(C3 + (size_t)(bS + key0 + r) * 1024 + h * 64 + c * 8, &Ks[buf][t * 512]);
    }
#pragma unroll
    for (int t = w; t < 8; t += 4) {   // V^T: 64 d-rows x 128B
      int ci = t * 64 + lane;
      int r = ci >> 3, c = (ci & 7) ^ (r & 7);
      load_lds16(Vt + (size_t)((size_t)bh * 64 + r) * 2048 + key0 + c * 8, &Vs[buf][t * 512]);
    }
  };

  stage(0, 0);
  for (int kt = 0; kt < nkt; ++kt) {
    __syncthreads();                    // drains vmcnt(0): stage(kt) visible to all
    const int c0 = kt * 64;
    const bool live = (c0 <= qb + 31);
    // Kr fragments from global, BEFORE next stage (FIFO vmcnt: waiting on these
    // does not force the stage DMAs to complete).
    bf16x8 kr[4];
    if (live) {
#pragma unroll
      for (int ni = 0; ni < 4; ++ni)
        kr[ni] = *(const bf16x8*)(Krr + (size_t)(bS + c0 + ni * 16 + ln) * 32 + quad * 8);
    }
    if (kt + 1 < nkt) stage((kt + 1) & 1, (kt + 1) * 64);
    if (!live) continue;                // fully-masked tile for this wave: barriers only

    const unsigned short* Kp = Ks[kt & 1];
    const unsigned short* Vp = Vs[kt & 1];

#pragma unroll
    for (int mi = 0; mi < 2; ++mi) {
      // ---- QK for this m-tile only (s: 4 x f32x4 live) ----
      f32x4 s[4];
#pragma unroll
      for (int ni = 0; ni < 4; ++ni) {
        int key = ni * 16 + ln;
        bf16x8 kf0 = *(const bf16x8*)(Kp + key * 64 + ((quad ^ (key & 7)) * 8));
        bf16x8 kf1 = *(const bf16x8*)(Kp + key * 64 + (((4 | quad) ^ (key & 7)) * 8));
        f32x4 acc = zero;
        acc = mfma16(qf[mi][0], kf0, acc);
        acc = mfma16(qf[mi][1], kf1, acc);
        acc = mfma16(qf[mi][2], kr[ni], acc);
        s[ni] = acc;
      }
      // ---- softmax (fixed max) -> P in LDS ----
      const bool nm = (c0 + 63) > (qb + mi * 16);  // tile touches the diagonal
      unsigned short* P = Ps[w];
#pragma unroll
      for (int ni = 0; ni < 4; ++ni)
#pragma unroll
        for (int r = 0; r < 4; ++r) {
          float t = fminf(fmaxf(s[ni][r], -80.f), 80.f);     // clip BEFORE scale (ref order)
          float z = fmaf(t, KSC, -KOFF);                     // z - M, z <= M guaranteed
          if (nm && (c0 + ni * 16 + ln) > (qb + mi * 16 + quad * 4 + r)) z = -1e30f;
          int q = quad * 4 + r;
          P[q * 64 + (((ni * 2 + (ln >> 3)) ^ (q & 7)) * 8) + (ln & 7)] = f2b(__expf(z));
        }
      LGKM_DRAIN();   // RAW: P writes visible; vmcnt (prefetch) untouched
      bf16x8 pf0 = *(const bf16x8*)(P + ln * 64 + ((quad ^ (ln & 7)) * 8));
      bf16x8 pf1 = *(const bf16x8*)(P + ln * 64 + (((4 | quad) ^ (ln & 7)) * 8));
      lacc[mi] = mfma16(pf0, kones, lacc[mi]);   // row-sum of P via MFMA
      lacc[mi] = mfma16(pf1, kones, lacc[mi]);
      // ---- PV with late V-fragment loads (no vf held across the tile) ----
#pragma unroll
      for (int nb = 0; nb < 4; ++nb) {
        int d = nb * 16 + ln;
        bf16x8 v0 = *(const bf16x8*)(Vp + d * 64 + ((quad ^ (d & 7)) * 8));
        bf16x8 v1 = *(const bf16x8*)(Vp + d * 64 + (((4 | quad) ^ (d & 7)) * 8));
        o[mi][nb] = mfma16(pf0, v0, o[mi][nb]);
        o[mi][nb] = mfma16(pf1, v1, o[mi][nb]);
      }
    }
  }

  // epilogue: Oa layout (B,S,H*64) bf16; lacc same C-layout as o
#pragma unroll
  for (int mi = 0; mi < 2; ++mi) {
    float rl[4];
#pragma unroll
    for (int r = 0; r < 4; ++r) rl[r] = 1.0f / lacc[mi][r];
#pragma unroll
    for (int nb = 0; nb < 4; ++nb)
#pragma unroll
      for (int r = 0; r < 4; ++r) {
        long row = (long)(bS + qb + mi * 16 + quad * 4 + r);
        Oa[row * 1024 + h * 64 + nb * 16 + ln] = f2b(o[mi][nb][r] * rl[r]);
      }
  }
}

// ---------------- launcher ----------------
extern "C" void kernel_launch(void* const* d_in, const int* in_sizes, int n_in,
                              void* d_out, int out_size, void* d_ws, size_t ws_size,
                              hipStream_t stream) {
  (void)in_sizes; (void)n_in; (void)out_size; (void)ws_size;
  const float* x     = (const float*)d_in[0];
  const float* W_DQ  = (const float*)d_in[1];
  const float* W_UQ  = (const float*)d_in[2];
  const float* W_QR  = (const float*)d_in[3];
  const float* W_DKV = (const float*)d_in[4];
  const float* W_UK  = (const float*)d_in[5];
  const float* W_UV  = (const float*)d_in[6];
  const float* W_KR  = (const float*)d_in[7];
  const float* W_O   = (const float*)d_in[8];

  char* p = (char*)d_ws;
  unsigned short* xb  = (unsigned short*)p; p += (size_t)8192 * 1024 * 2;
  unsigned short* WT1 = (unsigned short*)p; p += (size_t)544 * 1024 * 2;   // [W_DQ^T; W_DKV^T; W_KR^T]
  unsigned short* WT2 = (unsigned short*)p; p += (size_t)1536 * 256 * 2;   // [W_UQ^T; W_QR^T]
  unsigned short* WT3 = (unsigned short*)p; p += (size_t)2048 * 256 * 2;   // [W_UK^T; W_UV^T]
  unsigned short* WT4 = (unsigned short*)p; p += (size_t)1024 * 1024 * 2;  // W_O^T
  unsigned short* C1  = (unsigned short*)p; p += (size_t)8192 * 544 * 2;   // [c_q | c_kv | kr_raw]
  unsigned short* C2  = (unsigned short*)p; p += (size_t)8192 * 1536 * 2;  // [Qc | Qr(roped in-place)]
  unsigned short* C3  = (unsigned short*)p; p += (size_t)8192 * 1024 * 2;  // Kc only
  unsigned short* Krr = (unsigned short*)p; p += (size_t)8192 * 32 * 2;    // roped Kr
  unsigned short* Vt  = (unsigned short*)p; p += (size_t)64 * 64 * 2048 * 2;
  unsigned short* Oa  = (unsigned short*)p; p += (size_t)8192 * 1024 * 2;  // attn out (B,S,1024)

  convert_x<<<8192, 256, 0, stream>>>(x, xb);

  TWArgs tw;
  tw.W[0] = W_DQ;  tw.T[0] = WT1;
  tw.W[1] = W_DKV; tw.T[1] = WT1 + 256 * 1024;
  tw.W[2] = W_KR;  tw.T[2] = WT1 + 512 * 1024;
  tw.W[3] = W_UQ;  tw.T[3] = WT2;
  tw.W[4] = W_QR;  tw.T[4] = WT2 + 1024 * 256;
  tw.W[5] = W_UK;  tw.T[5] = WT3;
  tw.W[6] = W_UV;  tw.T[6] = WT3 + 1024 * 256;
  tw.W[7] = W_O;   tw.T[7] = WT4;
  transpose_w_all<<<2464, 256, 0, stream>>>(tw);

  gemm_bt<true><<<dim3(64, 5),  256, 0, stream>>>(xb, 1024, WT1, 1024, C1, 544, 544, 1024);
  gemm_bt<true><<<dim3(64, 12), 256, 0, stream>>>(C1, 544, WT2, 256, C2, 1536, 1536, 256);
  gemm_bt<true><<<dim3(64, 8),  256, 0, stream>>>(C1 + 256, 544, WT3, 256, C3, 1024, 1024, 256);
  gemm_bt_vt<<<dim3(64, 8),     256, 0, stream>>>(C1 + 256, 544, WT3 + 1024 * 256, 256, Vt, 256);
  rope_qk<<<8704, 256, 0, stream>>>(C2, C1, Krr);
  flash_attn<<<dim3(16, 64), 256, 0, stream>>>(C2, C3, Krr, Vt, Oa);
  gemm_bt<false><<<dim3(64, 8), 256, 0, stream>>>(Oa, 1024, WT4, 1024, d_out, 1024, 1024, 1024);
}

// Round 7
// 326.647 us; speedup vs baseline: 2.4687x; 1.1627x over previous
//
#include <hip/hip_runtime.h>
#include <hip/hip_bf16.h>

// MLA forward, MI355X/gfx950.
// B=4, S=2048, D_MODEL=1024, H=16, D_H=64, D_HR=32, D_LATENT=256, d_qk=96.

typedef __attribute__((ext_vector_type(8))) __bf16 bf16x8;
typedef __attribute__((ext_vector_type(4))) float f32x4;
typedef __attribute__((ext_vector_type(16))) float f32x16;
typedef __attribute__((ext_vector_type(4))) unsigned short us4;

#define DEV static __device__ __forceinline__

DEV unsigned short f2b(float f) {
  union { __hip_bfloat16 h; unsigned short u; } v;
  v.h = __float2bfloat16(f);
  return v.u;
}
DEV float b2f(unsigned short u) {
  union { unsigned short u; __hip_bfloat16 h; } v;
  v.u = u;
  return __bfloat162float(v.h);
}
DEV f32x4 mfma16(bf16x8 a, bf16x8 b, f32x4 c) {
  return __builtin_amdgcn_mfma_f32_16x16x32_bf16(a, b, c, 0, 0, 0);
}
DEV f32x16 mfma32(bf16x8 a, bf16x8 b, f32x16 c) {
  return __builtin_amdgcn_mfma_f32_32x32x16_bf16(a, b, c, 0, 0, 0);
}
DEV void load_lds16(const void* g, void* lds) {
  __builtin_amdgcn_global_load_lds((__attribute__((address_space(1))) void*)g,
                                   (__attribute__((address_space(3))) void*)lds,
                                   16, 0, 0);
}
// LDS-only drain: does NOT touch vmcnt, so global_load_lds prefetch stays in flight.
#define LGKM_DRAIN() __asm__ volatile("s_waitcnt lgkmcnt(0)" ::: "memory")

// ---------------- convert x (fp32 -> bf16) ----------------
__global__ __launch_bounds__(256) void convert_x(const float* __restrict__ x,
                                                 unsigned short* __restrict__ xb) {
  long i = (long)(blockIdx.x * 256 + threadIdx.x) * 4;
  float4 v = *(const float4*)(x + i);
  us4 o = { f2b(v.x), f2b(v.y), f2b(v.z), f2b(v.w) };
  *(us4*)(xb + i) = o;
}

// ---------------- batched weight transpose: 8 weights in ONE dispatch ----------------
struct TWArgs { const float* W[8]; unsigned short* T[8]; };
__global__ __launch_bounds__(256) void transpose_w_all(TWArgs a) {
  int bid = blockIdx.x;
  int g;
  if      (bid < 256)  g = 0;
  else if (bid < 512)  g = 1;
  else if (bid < 544)  g = 2;
  else if (bid < 800)  g = 3;
  else if (bid < 928)  g = 4;
  else if (bid < 1184) g = 5;
  else if (bid < 1440) g = 6;
  else                 g = 7;
  const int starts[8] = {0, 256, 512, 544, 800, 928, 1184, 1440};
  int local = bid - starts[g];
  int K = (g >= 3 && g <= 6) ? 256 : 1024;
  int N = (g < 2) ? 256 : (g == 2 ? 32 : (g == 4 ? 512 : 1024));
  int tilesX = N >> 5;
  int n0 = (local % tilesX) * 32, k0 = (local / tilesX) * 32;
  const float* W = a.W[g];
  unsigned short* WT = a.T[g];
  __shared__ float tile[32][33];
  int tx = threadIdx.x & 31, ty = threadIdx.x >> 5;
#pragma unroll
  for (int i = 0; i < 32; i += 8)
    tile[ty + i][tx] = W[(size_t)(k0 + ty + i) * N + n0 + tx];
  __syncthreads();
#pragma unroll
  for (int i = 0; i < 32; i += 8)
    WT[(size_t)(n0 + ty + i) * K + k0 + tx] = f2b(tile[tx][ty + i]);
}

// ---------------- fused RoPE: Qr in-place in C2, Kr C1->Krr ----------------
__global__ __launch_bounds__(256) void rope_qk(unsigned short* __restrict__ C2,
                                               const unsigned short* __restrict__ C1,
                                               unsigned short* __restrict__ Krr) {
  if (blockIdx.x < 8192) {
    int idx = blockIdx.x * 256 + threadIdx.x;   // 2^21 threads exact
    int i = idx & 15, h = (idx >> 4) & 15, s = (idx >> 8) & 2047, b = idx >> 19;
    long base = (long)(b * 2048 + s) * 1536 + 1024 + h * 32 + 2 * i;
    float x1 = b2f(C2[base]), x2 = b2f(C2[base + 1]);
    float inv = exp2f(-(float)i * 0.8304820237686285f);  // 10000^(-i/16)
    float ang = (float)s * inv;
    float c = cosf(ang), sn = sinf(ang);
    C2[base]     = f2b(x1 * c - x2 * sn);
    C2[base + 1] = f2b(x1 * sn + x2 * c);
  } else {
    int idx = (blockIdx.x - 8192) * 256 + threadIdx.x;   // 2^17 threads exact
    int i = idx & 15, s = (idx >> 4) & 2047, b = idx >> 15;
    long src = (long)(b * 2048 + s) * 544 + 512 + 2 * i;
    float x1 = b2f(C1[src]), x2 = b2f(C1[src + 1]);
    float inv = exp2f(-(float)i * 0.8304820237686285f);
    float ang = (float)s * inv;
    float c = cosf(ang), sn = sinf(ang);
    long dst = (long)(b * 2048 + s) * 32 + 2 * i;
    Krr[dst]     = f2b(x1 * c - x2 * sn);
    Krr[dst + 1] = f2b(x1 * sn + x2 * c);
  }
}

// ---------------- GEMM: C(M x N) = A(M x K, lda) @ Bt(N x K, ldb)^T ----------------
template <bool OUT_BF16>
__global__ __launch_bounds__(256) void gemm_bt(const unsigned short* __restrict__ A, int lda,
                                               const unsigned short* __restrict__ Bt, int ldb,
                                               void* __restrict__ Cv, int ldc, int N, int K) {
  __shared__ __align__(16) unsigned short As[128 * 32];
  __shared__ __align__(16) unsigned short Bs[128 * 32];
  const int t = threadIdx.x;
  const int w = t >> 6, lane = t & 63, ln = lane & 15, quad = lane >> 4;
  const int wr = w >> 1, wc = w & 1;
  const int bm0 = blockIdx.x * 128, bn0 = blockIdx.y * 128;
  const int srow = t >> 2;          // 0..63
  const int scol = (t & 3) * 8;     // 0,8,16,24
  f32x4 zero = {0.f, 0.f, 0.f, 0.f};
  f32x4 acc[4][4];
#pragma unroll
  for (int i = 0; i < 4; ++i)
#pragma unroll
    for (int j = 0; j < 4; ++j) acc[i][j] = zero;

  for (int k0 = 0; k0 < K; k0 += 32) {
#pragma unroll
    for (int r = 0; r < 2; ++r) {
      int arow = bm0 + r * 64 + srow;
      load_lds16(A + (long)arow * lda + k0 + scol, (char*)As + r * 4096 + w * 1024);
      int brow = bn0 + r * 64 + srow;
      if (brow > N - 1) brow = N - 1;  // clamp (garbage cols guarded at write)
      load_lds16(Bt + (long)brow * ldb + k0 + scol, (char*)Bs + r * 4096 + w * 1024);
    }
    __syncthreads();
    bf16x8 af[4], bf[4];
#pragma unroll
    for (int i = 0; i < 4; ++i)
      af[i] = *(const bf16x8*)(As + (wr * 64 + i * 16 + ln) * 32 + quad * 8);
#pragma unroll
    for (int j = 0; j < 4; ++j)
      bf[j] = *(const bf16x8*)(Bs + (wc * 64 + j * 16 + ln) * 32 + quad * 8);
#pragma unroll
    for (int i = 0; i < 4; ++i)
#pragma unroll
      for (int j = 0; j < 4; ++j) acc[i][j] = mfma16(af[i], bf[j], acc[i][j]);
    __syncthreads();
  }
#pragma unroll
  for (int i = 0; i < 4; ++i)
#pragma unroll
    for (int j = 0; j < 4; ++j)
#pragma unroll
      for (int r = 0; r < 4; ++r) {
        int row = bm0 + wr * 64 + i * 16 + quad * 4 + r;
        int col = bn0 + wc * 64 + j * 16 + ln;
        if (col < N) {
          if (OUT_BF16)
            ((unsigned short*)Cv)[(long)row * ldc + col] = f2b(acc[i][j][r]);
          else
            ((float*)Cv)[(long)row * ldc + col] = acc[i][j][r];
        }
      }
}

// ---------------- V GEMM with transposed epilogue: writes Vt[bh*64+d][s] directly ----------------
__global__ __launch_bounds__(256) void gemm_bt_vt(const unsigned short* __restrict__ A, int lda,
                                                  const unsigned short* __restrict__ Bt, int ldb,
                                                  unsigned short* __restrict__ Vt, int K) {
  __shared__ __align__(16) unsigned short As[128 * 32];
  __shared__ __align__(16) unsigned short Bs[128 * 32];
  const int t = threadIdx.x;
  const int w = t >> 6, lane = t & 63, ln = lane & 15, quad = lane >> 4;
  const int wr = w >> 1, wc = w & 1;
  const int bm0 = blockIdx.x * 128, bn0 = blockIdx.y * 128;
  const int srow = t >> 2, scol = (t & 3) * 8;
  f32x4 zero = {0.f, 0.f, 0.f, 0.f};
  f32x4 acc[4][4];
#pragma unroll
  for (int i = 0; i < 4; ++i)
#pragma unroll
    for (int j = 0; j < 4; ++j) acc[i][j] = zero;

  for (int k0 = 0; k0 < K; k0 += 32) {
#pragma unroll
    for (int r = 0; r < 2; ++r) {
      load_lds16(A + (long)(bm0 + r * 64 + srow) * lda + k0 + scol, (char*)As + r * 4096 + w * 1024);
      load_lds16(Bt + (long)(bn0 + r * 64 + srow) * ldb + k0 + scol, (char*)Bs + r * 4096 + w * 1024);
    }
    __syncthreads();
    bf16x8 af[4], bf[4];
#pragma unroll
    for (int i = 0; i < 4; ++i)
      af[i] = *(const bf16x8*)(As + (wr * 64 + i * 16 + ln) * 32 + quad * 8);
#pragma unroll
    for (int j = 0; j < 4; ++j)
      bf[j] = *(const bf16x8*)(Bs + (wc * 64 + j * 16 + ln) * 32 + quad * 8);
#pragma unroll
    for (int i = 0; i < 4; ++i)
#pragma unroll
      for (int j = 0; j < 4; ++j) acc[i][j] = mfma16(af[i], bf[j], acc[i][j]);
    __syncthreads();
  }
#pragma unroll
  for (int i = 0; i < 4; ++i)
#pragma unroll
    for (int j = 0; j < 4; ++j) {
      int col = bn0 + wc * 64 + j * 16 + ln;          // 0..1023 = h*64+d
      int row0 = bm0 + wr * 64 + i * 16 + quad * 4;   // 4 consecutive seq rows, same b
      int b = row0 >> 11, sl = row0 & 2047;
      us4 pk = { f2b(acc[i][j][0]), f2b(acc[i][j][1]), f2b(acc[i][j][2]), f2b(acc[i][j][3]) };
      *(us4*)(Vt + ((size_t)(b * 16) * 64 + col) * 2048 + sl) = pk;
    }
}

// ---------------- Flash attention v5: 32x32 MFMA, in-register P ----------------
// grid (16, 64), qi = 15-x (LPT). Wave owns 32 q-rows; 64-key double-buffered tiles.
// S^T = K·Q^T via mfma_32x32x16 (A = K rows staged with key-permutation pi =
// swap bits 2,3 of key&15; B = Q rows read directly from C2 as b128).
// With pi on K staging, the exp'd S^T C-registers ARE the PV A-operand
// fragments for V in NATURAL key order (pi(m'(j,h)) == h*8+j identity), so P
// never touches LDS. Row-sum l is a per-lane scalar (each lane owns one q).
// LDS traffic/wave-tile: 16 b128 reads, 0 writes (was ~36 reads + 32 b16 writes).
__global__ __launch_bounds__(256, 3) void flash_attn(const unsigned short* __restrict__ C2,
                                                     const unsigned short* __restrict__ C3,
                                                     const unsigned short* __restrict__ Krr,
                                                     const unsigned short* __restrict__ Vt,
                                                     unsigned short* __restrict__ Oa) {
  __shared__ __align__(16) unsigned short Ks[2][4096];  // 64 keys(pi-staged) x 64 d, chunk-swizzled
  __shared__ __align__(16) unsigned short Vs[2][4096];  // 64 d x 64 keys(natural), chunk-swizzled
  __shared__ float Ls[4][32];

  const int tid = threadIdx.x;
  const int w = tid >> 6, lane = tid & 63;
  const int l31 = lane & 31, h = lane >> 5;
  const int bh = blockIdx.y, b = bh >> 4, head = bh & 15;
  const int bS = b * 2048;
  const int qi = 15 - blockIdx.x;          // LPT order
  const int qb = qi * 128 + w * 32;
  const int nkt = 2 * qi + 2;
  const float KSC  = 0.10206207261596577f;  // 1/sqrt(96)
  const float KOFF = 8.16496580927726f;     // 80/sqrt(96): bound on clipped*scaled score
  const int q = qb + l31;                   // this lane's q row
  const int pr = (l31 & ~12) | ((l31 & 4) << 1) | ((l31 & 8) >> 1);  // pi(l31)

  // Q B-operand fragments: per lane row q, 8 d's at (lane>>5)*8 -- direct b128 reads.
  const unsigned short* qp = C2 + (size_t)(bS + q) * 1536;
  bf16x8 qf[6];
#pragma unroll
  for (int c = 0; c < 4; ++c)
    qf[c] = *(const bf16x8*)(qp + head * 64 + c * 16 + h * 8);
#pragma unroll
  for (int c = 4; c < 6; ++c)
    qf[c] = *(const bf16x8*)(qp + 1024 + head * 32 + (c - 4) * 16 + h * 8);

  f32x16 o0 = {}, o1 = {};
  float lsum = 0.f;

  auto stage = [&](int buf, int key0) {
#pragma unroll
    for (int t = w; t < 8; t += 4) {   // K: dest row r <- source key key0+pi(r)
      int ci = t * 64 + lane;
      int r = ci >> 3, sl = ci & 7;
      int srcc = sl ^ (r & 7);
      int srck = (r & ~12) | ((r & 4) << 1) | ((r & 8) >> 1);
      load_lds16(C3 + (size_t)(bS + key0 + srck) * 1024 + head * 64 + srcc * 8,
                 &Ks[buf][t * 512]);
    }
#pragma unroll
    for (int t = w; t < 8; t += 4) {   // V^T: natural key order
      int ci = t * 64 + lane;
      int r = ci >> 3, sl = ci & 7;
      int srcc = sl ^ (r & 7);
      load_lds16(Vt + (size_t)((size_t)bh * 64 + r) * 2048 + key0 + srcc * 8,
                 &Vs[buf][t * 512]);
    }
  };

  stage(0, 0);
  for (int kt = 0; kt < nkt; ++kt) {
    __syncthreads();                    // drains vmcnt(0): stage(kt) visible
    const int c0 = kt * 64;
    const bool live = (c0 <= qb + 31);
    bf16x8 kr[4];                       // Kr A-frags from global (pi rows), BEFORE next stage
    if (live) {
#pragma unroll
      for (int m = 0; m < 2; ++m)
#pragma unroll
        for (int c = 0; c < 2; ++c)
          kr[m * 2 + c] = *(const bf16x8*)(Krr + (size_t)(bS + c0 + m * 32 + pr) * 32 +
                                           c * 16 + h * 8);
    }
    if (kt + 1 < nkt) stage((kt + 1) & 1, c0 + 64);
    if (!live) continue;

    const unsigned short* Kp = Ks[kt & 1];
    const unsigned short* Vp = Vs[kt & 1];

#pragma unroll
    for (int m = 0; m < 2; ++m) {
      if (c0 + m * 32 > qb + 31) continue;   // m-tile fully masked for this wave
      const int r = m * 32 + l31;            // staged K row this lane reads
      f32x16 s = {};
#pragma unroll
      for (int c = 0; c < 4; ++c) {
        int slot = (2 * c + h) ^ (r & 7);
        bf16x8 kf = *(const bf16x8*)(Kp + r * 64 + slot * 8);
        s = mfma32(kf, qf[c], s);
      }
      s = mfma32(kr[m * 2 + 0], qf[4], s);
      s = mfma32(kr[m * 2 + 1], qf[5], s);

      // exp in-register; actual key of reg p = c0+m*32+(p&3)+4*((p>>2)&1)+8h+16*(p>>3)
      const bool nm = (c0 + m * 32 + 31) > qb;   // touches diagonal for this wave
      float ev[16];
#pragma unroll
      for (int p = 0; p < 16; ++p) {
        float t = fminf(fmaxf(s[p], -80.f), 80.f);   // clip BEFORE scale (ref order)
        float z = fmaf(t, KSC, -KOFF);               // z <= 0 guaranteed
        if (nm) {
          int key = c0 + m * 32 + (p & 3) + 4 * ((p >> 2) & 1) + 8 * h + 16 * (p >> 3);
          if (key > q) z = -1e30f;
        }
        float e = __expf(z);
        lsum += e;
        ev[p] = e;
      }
      bf16x8 pf[2];
#pragma unroll
      for (int t = 0; t < 2; ++t) {
        union { unsigned short u[8]; bf16x8 v; } pk;
#pragma unroll
        for (int j = 0; j < 8; ++j) pk.u[j] = f2b(ev[t * 8 + j]);
        pf[t] = pk.v;
      }
      // PV: A = pf (keys natural order by pi-identity), B = V fragments from Vs
#pragma unroll
      for (int t = 0; t < 2; ++t) {
        int tk = m * 2 + t;
#pragma unroll
        for (int n = 0; n < 2; ++n) {
          int rr = n * 32 + l31;
          int slot = (2 * tk + h) ^ (rr & 7);
          bf16x8 vf = *(const bf16x8*)(Vp + rr * 64 + slot * 8);
          if (n == 0) o0 = mfma32(pf[t], vf, o0);
          else        o1 = mfma32(pf[t], vf, o1);
        }
      }
    }
  }

  // ---- epilogue ----
  float lfull = lsum + __shfl_xor(lsum, 32);   // combine the two key-halves of q
  Ls[w][l31] = lfull;                           // both halves write same value
  LGKM_DRAIN();                                 // per-wave RAW on Ls
#pragma unroll
  for (int p = 0; p < 16; ++p) {
    int qrow = (p & 3) + 8 * (p >> 2) + 4 * h;  // o C-layout row
    float rl = 1.0f / Ls[w][qrow];
    size_t base = (size_t)(bS + qb + qrow) * 1024 + head * 64;
    Oa[base + l31]      = f2b(o0[p] * rl);
    Oa[base + 32 + l31] = f2b(o1[p] * rl);
  }
}

// ---------------- launcher ----------------
extern "C" void kernel_launch(void* const* d_in, const int* in_sizes, int n_in,
                              void* d_out, int out_size, void* d_ws, size_t ws_size,
                              hipStream_t stream) {
  (void)in_sizes; (void)n_in; (void)out_size; (void)ws_size;
  const float* x     = (const float*)d_in[0];
  const float* W_DQ  = (const float*)d_in[1];
  const float* W_UQ  = (const float*)d_in[2];
  const float* W_QR  = (const float*)d_in[3];
  const float* W_DKV = (const float*)d_in[4];
  const float* W_UK  = (const float*)d_in[5];
  const float* W_UV  = (const float*)d_in[6];
  const float* W_KR  = (const float*)d_in[7];
  const float* W_O   = (const float*)d_in[8];

  char* p = (char*)d_ws;
  unsigned short* xb  = (unsigned short*)p; p += (size_t)8192 * 1024 * 2;
  unsigned short* WT1 = (unsigned short*)p; p += (size_t)544 * 1024 * 2;   // [W_DQ^T; W_DKV^T; W_KR^T]
  unsigned short* WT2 = (unsigned short*)p; p += (size_t)1536 * 256 * 2;   // [W_UQ^T; W_QR^T]
  unsigned short* WT3 = (unsigned short*)p; p += (size_t)2048 * 256 * 2;   // [W_UK^T; W_UV^T]
  unsigned short* WT4 = (unsigned short*)p; p += (size_t)1024 * 1024 * 2;  // W_O^T
  unsigned short* C1  = (unsigned short*)p; p += (size_t)8192 * 544 * 2;   // [c_q | c_kv | kr_raw]
  unsigned short* C2  = (unsigned short*)p; p += (size_t)8192 * 1536 * 2;  // [Qc | Qr(roped in-place)]
  unsigned short* C3  = (unsigned short*)p; p += (size_t)8192 * 1024 * 2;  // Kc only
  unsigned short* Krr = (unsigned short*)p; p += (size_t)8192 * 32 * 2;    // roped Kr
  unsigned short* Vt  = (unsigned short*)p; p += (size_t)64 * 64 * 2048 * 2;
  unsigned short* Oa  = (unsigned short*)p; p += (size_t)8192 * 1024 * 2;  // attn out (B,S,1024)

  convert_x<<<8192, 256, 0, stream>>>(x, xb);

  TWArgs tw;
  tw.W[0] = W_DQ;  tw.T[0] = WT1;
  tw.W[1] = W_DKV; tw.T[1] = WT1 + 256 * 1024;
  tw.W[2] = W_KR;  tw.T[2] = WT1 + 512 * 1024;
  tw.W[3] = W_UQ;  tw.T[3] = WT2;
  tw.W[4] = W_QR;  tw.T[4] = WT2 + 1024 * 256;
  tw.W[5] = W_UK;  tw.T[5] = WT3;
  tw.W[6] = W_UV;  tw.T[6] = WT3 + 1024 * 256;
  tw.W[7] = W_O;   tw.T[7] = WT4;
  transpose_w_all<<<2464, 256, 0, stream>>>(tw);

  gemm_bt<true><<<dim3(64, 5),  256, 0, stream>>>(xb, 1024, WT1, 1024, C1, 544, 544, 1024);
  gemm_bt<true><<<dim3(64, 12), 256, 0, stream>>>(C1, 544, WT2, 256, C2, 1536, 1536, 256);
  gemm_bt<true><<<dim3(64, 8),  256, 0, stream>>>(C1 + 256, 544, WT3, 256, C3, 1024, 1024, 256);
  gemm_bt_vt<<<dim3(64, 8),     256, 0, stream>>>(C1 + 256, 544, WT3 + 1024 * 256, 256, Vt, 256);
  rope_qk<<<8704, 256, 0, stream>>>(C2, C1, Krr);
  flash_attn<<<dim3(16, 64), 256, 0, stream>>>(C2, C3, Krr, Vt, Oa);
  gemm_bt<false><<<dim3(64, 8), 256, 0, stream>>>(Oa, 1024, WT4, 1024, d_out, 1024, 1024, 1024);
}

// Round 8
// 281.923 us; speedup vs baseline: 2.8603x; 1.1586x over previous
//
#include <hip/hip_runtime.h>
#include <hip/hip_bf16.h>

// MLA forward, MI355X/gfx950.
// B=4, S=2048, D_MODEL=1024, H=16, D_H=64, D_HR=32, D_LATENT=256, d_qk=96.

typedef __attribute__((ext_vector_type(8))) __bf16 bf16x8;
typedef __attribute__((ext_vector_type(4))) float f32x4;
typedef __attribute__((ext_vector_type(16))) float f32x16;
typedef __attribute__((ext_vector_type(4))) unsigned short us4;

#define DEV static __device__ __forceinline__

DEV unsigned short f2b(float f) {
  union { __hip_bfloat16 h; unsigned short u; } v;
  v.h = __float2bfloat16(f);
  return v.u;
}
DEV float b2f(unsigned short u) {
  union { unsigned short u; __hip_bfloat16 h; } v;
  v.u = u;
  return __bfloat162float(v.h);
}
DEV unsigned int f2b2(float lo, float hi) {   // packed 2xf32 -> 2xbf16
  union { __hip_bfloat162 h2; unsigned int u; } v;
  float2 t; t.x = lo; t.y = hi;
  v.h2 = __float22bfloat162_rn(t);
  return v.u;
}
DEV f32x4 mfma16(bf16x8 a, bf16x8 b, f32x4 c) {
  return __builtin_amdgcn_mfma_f32_16x16x32_bf16(a, b, c, 0, 0, 0);
}
DEV f32x16 mfma32(bf16x8 a, bf16x8 b, f32x16 c) {
  return __builtin_amdgcn_mfma_f32_32x32x16_bf16(a, b, c, 0, 0, 0);
}
DEV void load_lds16(const void* g, void* lds) {
  __builtin_amdgcn_global_load_lds((__attribute__((address_space(1))) void*)g,
                                   (__attribute__((address_space(3))) void*)lds,
                                   16, 0, 0);
}
// LDS-only drain: does NOT touch vmcnt, so global_load_lds prefetch stays in flight.
#define LGKM_DRAIN() __asm__ volatile("s_waitcnt lgkmcnt(0)" ::: "memory")

// ---------------- convert x (fp32 -> bf16) ----------------
__global__ __launch_bounds__(256) void convert_x(const float* __restrict__ x,
                                                 unsigned short* __restrict__ xb) {
  long i = (long)(blockIdx.x * 256 + threadIdx.x) * 4;
  float4 v = *(const float4*)(x + i);
  us4 o = { f2b(v.x), f2b(v.y), f2b(v.z), f2b(v.w) };
  *(us4*)(xb + i) = o;
}

// ---------------- batched weight transpose: 8 weights in ONE dispatch ----------------
struct TWArgs { const float* W[8]; unsigned short* T[8]; };
__global__ __launch_bounds__(256) void transpose_w_all(TWArgs a) {
  int bid = blockIdx.x;
  int g;
  if      (bid < 256)  g = 0;
  else if (bid < 512)  g = 1;
  else if (bid < 544)  g = 2;
  else if (bid < 800)  g = 3;
  else if (bid < 928)  g = 4;
  else if (bid < 1184) g = 5;
  else if (bid < 1440) g = 6;
  else                 g = 7;
  const int starts[8] = {0, 256, 512, 544, 800, 928, 1184, 1440};
  int local = bid - starts[g];
  int K = (g >= 3 && g <= 6) ? 256 : 1024;
  int N = (g < 2) ? 256 : (g == 2 ? 32 : (g == 4 ? 512 : 1024));
  int tilesX = N >> 5;
  int n0 = (local % tilesX) * 32, k0 = (local / tilesX) * 32;
  const float* W = a.W[g];
  unsigned short* WT = a.T[g];
  __shared__ float tile[32][33];
  int tx = threadIdx.x & 31, ty = threadIdx.x >> 5;
#pragma unroll
  for (int i = 0; i < 32; i += 8)
    tile[ty + i][tx] = W[(size_t)(k0 + ty + i) * N + n0 + tx];
  __syncthreads();
#pragma unroll
  for (int i = 0; i < 32; i += 8)
    WT[(size_t)(n0 + ty + i) * K + k0 + tx] = f2b(tile[tx][ty + i]);
}

// ---------------- fused RoPE: Qr in-place in C2, Kr C1->Krr ----------------
__global__ __launch_bounds__(256) void rope_qk(unsigned short* __restrict__ C2,
                                               const unsigned short* __restrict__ C1,
                                               unsigned short* __restrict__ Krr) {
  if (blockIdx.x < 8192) {
    int idx = blockIdx.x * 256 + threadIdx.x;   // 2^21 threads exact
    int i = idx & 15, h = (idx >> 4) & 15, s = (idx >> 8) & 2047, b = idx >> 19;
    long base = (long)(b * 2048 + s) * 1536 + 1024 + h * 32 + 2 * i;
    float x1 = b2f(C2[base]), x2 = b2f(C2[base + 1]);
    float inv = exp2f(-(float)i * 0.8304820237686285f);  // 10000^(-i/16)
    float ang = (float)s * inv;
    float c = cosf(ang), sn = sinf(ang);
    C2[base]     = f2b(x1 * c - x2 * sn);
    C2[base + 1] = f2b(x1 * sn + x2 * c);
  } else {
    int idx = (blockIdx.x - 8192) * 256 + threadIdx.x;   // 2^17 threads exact
    int i = idx & 15, s = (idx >> 4) & 2047, b = idx >> 15;
    long src = (long)(b * 2048 + s) * 544 + 512 + 2 * i;
    float x1 = b2f(C1[src]), x2 = b2f(C1[src + 1]);
    float inv = exp2f(-(float)i * 0.8304820237686285f);
    float ang = (float)s * inv;
    float c = cosf(ang), sn = sinf(ang);
    long dst = (long)(b * 2048 + s) * 32 + 2 * i;
    Krr[dst]     = f2b(x1 * c - x2 * sn);
    Krr[dst + 1] = f2b(x1 * sn + x2 * c);
  }
}

// ---------------- GEMM: C(M x N) = A(M x K, lda) @ Bt(N x K, ldb)^T ----------------
template <bool OUT_BF16>
__global__ __launch_bounds__(256) void gemm_bt(const unsigned short* __restrict__ A, int lda,
                                               const unsigned short* __restrict__ Bt, int ldb,
                                               void* __restrict__ Cv, int ldc, int N, int K) {
  __shared__ __align__(16) unsigned short As[128 * 32];
  __shared__ __align__(16) unsigned short Bs[128 * 32];
  const int t = threadIdx.x;
  const int w = t >> 6, lane = t & 63, ln = lane & 15, quad = lane >> 4;
  const int wr = w >> 1, wc = w & 1;
  const int bm0 = blockIdx.x * 128, bn0 = blockIdx.y * 128;
  const int srow = t >> 2;          // 0..63
  const int scol = (t & 3) * 8;     // 0,8,16,24
  f32x4 zero = {0.f, 0.f, 0.f, 0.f};
  f32x4 acc[4][4];
#pragma unroll
  for (int i = 0; i < 4; ++i)
#pragma unroll
    for (int j = 0; j < 4; ++j) acc[i][j] = zero;

  for (int k0 = 0; k0 < K; k0 += 32) {
#pragma unroll
    for (int r = 0; r < 2; ++r) {
      int arow = bm0 + r * 64 + srow;
      load_lds16(A + (long)arow * lda + k0 + scol, (char*)As + r * 4096 + w * 1024);
      int brow = bn0 + r * 64 + srow;
      if (brow > N - 1) brow = N - 1;  // clamp (garbage cols guarded at write)
      load_lds16(Bt + (long)brow * ldb + k0 + scol, (char*)Bs + r * 4096 + w * 1024);
    }
    __syncthreads();
    bf16x8 af[4], bf[4];
#pragma unroll
    for (int i = 0; i < 4; ++i)
      af[i] = *(const bf16x8*)(As + (wr * 64 + i * 16 + ln) * 32 + quad * 8);
#pragma unroll
    for (int j = 0; j < 4; ++j)
      bf[j] = *(const bf16x8*)(Bs + (wc * 64 + j * 16 + ln) * 32 + quad * 8);
#pragma unroll
    for (int i = 0; i < 4; ++i)
#pragma unroll
      for (int j = 0; j < 4; ++j) acc[i][j] = mfma16(af[i], bf[j], acc[i][j]);
    __syncthreads();
  }
#pragma unroll
  for (int i = 0; i < 4; ++i)
#pragma unroll
    for (int j = 0; j < 4; ++j)
#pragma unroll
      for (int r = 0; r < 4; ++r) {
        int row = bm0 + wr * 64 + i * 16 + quad * 4 + r;
        int col = bn0 + wc * 64 + j * 16 + ln;
        if (col < N) {
          if (OUT_BF16)
            ((unsigned short*)Cv)[(long)row * ldc + col] = f2b(acc[i][j][r]);
          else
            ((float*)Cv)[(long)row * ldc + col] = acc[i][j][r];
        }
      }
}

// ---------------- V GEMM with transposed epilogue: writes Vt[bh*64+d][s] directly ----------------
__global__ __launch_bounds__(256) void gemm_bt_vt(const unsigned short* __restrict__ A, int lda,
                                                  const unsigned short* __restrict__ Bt, int ldb,
                                                  unsigned short* __restrict__ Vt, int K) {
  __shared__ __align__(16) unsigned short As[128 * 32];
  __shared__ __align__(16) unsigned short Bs[128 * 32];
  const int t = threadIdx.x;
  const int w = t >> 6, lane = t & 63, ln = lane & 15, quad = lane >> 4;
  const int wr = w >> 1, wc = w & 1;
  const int bm0 = blockIdx.x * 128, bn0 = blockIdx.y * 128;
  const int srow = t >> 2, scol = (t & 3) * 8;
  f32x4 zero = {0.f, 0.f, 0.f, 0.f};
  f32x4 acc[4][4];
#pragma unroll
  for (int i = 0; i < 4; ++i)
#pragma unroll
    for (int j = 0; j < 4; ++j) acc[i][j] = zero;

  for (int k0 = 0; k0 < K; k0 += 32) {
#pragma unroll
    for (int r = 0; r < 2; ++r) {
      load_lds16(A + (long)(bm0 + r * 64 + srow) * lda + k0 + scol, (char*)As + r * 4096 + w * 1024);
      load_lds16(Bt + (long)(bn0 + r * 64 + srow) * ldb + k0 + scol, (char*)Bs + r * 4096 + w * 1024);
    }
    __syncthreads();
    bf16x8 af[4], bf[4];
#pragma unroll
    for (int i = 0; i < 4; ++i)
      af[i] = *(const bf16x8*)(As + (wr * 64 + i * 16 + ln) * 32 + quad * 8);
#pragma unroll
    for (int j = 0; j < 4; ++j)
      bf[j] = *(const bf16x8*)(Bs + (wc * 64 + j * 16 + ln) * 32 + quad * 8);
#pragma unroll
    for (int i = 0; i < 4; ++i)
#pragma unroll
      for (int j = 0; j < 4; ++j) acc[i][j] = mfma16(af[i], bf[j], acc[i][j]);
    __syncthreads();
  }
#pragma unroll
  for (int i = 0; i < 4; ++i)
#pragma unroll
    for (int j = 0; j < 4; ++j) {
      int col = bn0 + wc * 64 + j * 16 + ln;          // 0..1023 = h*64+d
      int row0 = bm0 + wr * 64 + i * 16 + quad * 4;   // 4 consecutive seq rows, same b
      int b = row0 >> 11, sl = row0 & 2047;
      us4 pk = { f2b(acc[i][j][0]), f2b(acc[i][j][1]), f2b(acc[i][j][2]), f2b(acc[i][j][3]) };
      *(us4*)(Vt + ((size_t)(b * 16) * 64 + col) * 2048 + sl) = pk;
    }
}

// ---------------- Flash attention v6: 32x32 MFMA, in-register P, balanced grid ----------------
// grid (64, 16): x = bh, y -> qi = 15-y. Linear id = bh + 64*y, so co-resident
// blocks (ids congruent mod 256) differ in y by {0,4,8,12} -> per-CU causal work
// spread ~12 units instead of ~120 (the R7 grid aliased same-qi blocks onto one CU).
// S^T = K·Q^T via mfma_32x32x16 with pi-staged K rows; exp'd S^T registers ARE the
// PV A-fragments (pi identity); P never touches LDS. exp via exp2 (log2e folded
// into scale), fmed3 clip, packed bf16 cvt.
__global__ __launch_bounds__(256, 3) void flash_attn(const unsigned short* __restrict__ C2,
                                                     const unsigned short* __restrict__ C3,
                                                     const unsigned short* __restrict__ Krr,
                                                     const unsigned short* __restrict__ Vt,
                                                     unsigned short* __restrict__ Oa) {
  __shared__ __align__(16) unsigned short Ks[2][4096];  // 64 keys(pi-staged) x 64 d, chunk-swizzled
  __shared__ __align__(16) unsigned short Vs[2][4096];  // 64 d x 64 keys(natural), chunk-swizzled
  __shared__ float Ls[4][32];

  const int tid = threadIdx.x;
  const int w = tid >> 6, lane = tid & 63;
  const int l31 = lane & 31, h = lane >> 5;
  const int bh = blockIdx.x, b = bh >> 4, head = bh & 15;
  const int bS = b * 2048;
  const int qi = 15 - blockIdx.y;
  const int qb = qi * 128 + w * 32;
  const int nkt = 2 * qi + 2;
  const float KSC2  = 0.14724444690f;   // (1/sqrt(96)) * log2(e)
  const float KOFF2 = 11.7795557220f;   // (80/sqrt(96)) * log2(e)
  const int q = qb + l31;               // this lane's q row
  const int pr = (l31 & ~12) | ((l31 & 4) << 1) | ((l31 & 8) >> 1);  // pi(l31)

  // Q B-operand fragments: per lane row q, 8 d's at h*8 -- direct b128 reads.
  const unsigned short* qp = C2 + (size_t)(bS + q) * 1536;
  bf16x8 qf[6];
#pragma unroll
  for (int c = 0; c < 4; ++c)
    qf[c] = *(const bf16x8*)(qp + head * 64 + c * 16 + h * 8);
#pragma unroll
  for (int c = 4; c < 6; ++c)
    qf[c] = *(const bf16x8*)(qp + 1024 + head * 32 + (c - 4) * 16 + h * 8);

  f32x16 o0 = {}, o1 = {};
  float lsum = 0.f;

  auto stage = [&](int buf, int key0) {
#pragma unroll
    for (int t = w; t < 8; t += 4) {   // K: dest row r <- source key key0+pi(r)
      int ci = t * 64 + lane;
      int r = ci >> 3, sl = ci & 7;
      int srcc = sl ^ (r & 7);
      int srck = (r & ~12) | ((r & 4) << 1) | ((r & 8) >> 1);
      load_lds16(C3 + (size_t)(bS + key0 + srck) * 1024 + head * 64 + srcc * 8,
                 &Ks[buf][t * 512]);
    }
#pragma unroll
    for (int t = w; t < 8; t += 4) {   // V^T: natural key order
      int ci = t * 64 + lane;
      int r = ci >> 3, sl = ci & 7;
      int srcc = sl ^ (r & 7);
      load_lds16(Vt + (size_t)((size_t)bh * 64 + r) * 2048 + key0 + srcc * 8,
                 &Vs[buf][t * 512]);
    }
  };

  stage(0, 0);
  for (int kt = 0; kt < nkt; ++kt) {
    __syncthreads();                    // drains vmcnt(0): stage(kt) visible
    const int c0 = kt * 64;
    const bool live = (c0 <= qb + 31);
    bf16x8 kr[4];                       // Kr A-frags from global (pi rows), BEFORE next stage
    if (live) {
#pragma unroll
      for (int m = 0; m < 2; ++m)
#pragma unroll
        for (int c = 0; c < 2; ++c)
          kr[m * 2 + c] = *(const bf16x8*)(Krr + (size_t)(bS + c0 + m * 32 + pr) * 32 +
                                           c * 16 + h * 8);
    }
    if (kt + 1 < nkt) stage((kt + 1) & 1, c0 + 64);
    if (!live) continue;

    const unsigned short* Kp = Ks[kt & 1];
    const unsigned short* Vp = Vs[kt & 1];

#pragma unroll
    for (int m = 0; m < 2; ++m) {
      if (c0 + m * 32 > qb + 31) continue;   // m-tile fully masked for this wave
      const int r = m * 32 + l31;            // staged K row this lane reads
      f32x16 s = {};
#pragma unroll
      for (int c = 0; c < 4; ++c) {
        int slot = (2 * c + h) ^ (r & 7);
        bf16x8 kf = *(const bf16x8*)(Kp + r * 64 + slot * 8);
        s = mfma32(kf, qf[c], s);
      }
      s = mfma32(kr[m * 2 + 0], qf[4], s);
      s = mfma32(kr[m * 2 + 1], qf[5], s);

      // exp in-register; actual key of reg p = c0+m*32+(p&3)+4*((p>>2)&1)+8h+16*(p>>3)
      const bool nm = (c0 + m * 32 + 31) > qb;   // touches diagonal for this wave
      float ev[16];
#pragma unroll
      for (int p = 0; p < 16; ++p) {
        float t = __builtin_amdgcn_fmed3f(s[p], -80.f, 80.f);  // clip BEFORE scale (ref order)
        float z = fmaf(t, KSC2, -KOFF2);                       // log2-domain, z <= ~0
        if (nm) {
          int key = c0 + m * 32 + (p & 3) + 4 * ((p >> 2) & 1) + 8 * h + 16 * (p >> 3);
          if (key > q) z = -1e30f;
        }
        float e = exp2f(z);
        lsum += e;
        ev[p] = e;
      }
      bf16x8 pf[2];
#pragma unroll
      for (int t = 0; t < 2; ++t) {
        union { unsigned int u[4]; bf16x8 v; } pk;
#pragma unroll
        for (int j = 0; j < 4; ++j)
          pk.u[j] = f2b2(ev[t * 8 + 2 * j], ev[t * 8 + 2 * j + 1]);
        pf[t] = pk.v;
      }
      // PV: A = pf (keys natural order by pi-identity), B = V fragments from Vs
#pragma unroll
      for (int t = 0; t < 2; ++t) {
        int tk = m * 2 + t;
#pragma unroll
        for (int n = 0; n < 2; ++n) {
          int rr = n * 32 + l31;
          int slot = (2 * tk + h) ^ (rr & 7);
          bf16x8 vf = *(const bf16x8*)(Vp + rr * 64 + slot * 8);
          if (n == 0) o0 = mfma32(pf[t], vf, o0);
          else        o1 = mfma32(pf[t], vf, o1);
        }
      }
    }
  }

  // ---- epilogue ----
  float lfull = lsum + __shfl_xor(lsum, 32);   // combine the two key-halves of q
  Ls[w][l31] = lfull;                           // both halves write same value
  LGKM_DRAIN();                                 // per-wave RAW on Ls
#pragma unroll
  for (int p = 0; p < 16; ++p) {
    int qrow = (p & 3) + 8 * (p >> 2) + 4 * h;  // o C-layout row
    float rl = 1.0f / Ls[w][qrow];
    size_t base = (size_t)(bS + qb + qrow) * 1024 + head * 64;
    Oa[base + l31]      = f2b(o0[p] * rl);
    Oa[base + 32 + l31] = f2b(o1[p] * rl);
  }
}

// ---------------- launcher ----------------
extern "C" void kernel_launch(void* const* d_in, const int* in_sizes, int n_in,
                              void* d_out, int out_size, void* d_ws, size_t ws_size,
                              hipStream_t stream) {
  (void)in_sizes; (void)n_in; (void)out_size; (void)ws_size;
  const float* x     = (const float*)d_in[0];
  const float* W_DQ  = (const float*)d_in[1];
  const float* W_UQ  = (const float*)d_in[2];
  const float* W_QR  = (const float*)d_in[3];
  const float* W_DKV = (const float*)d_in[4];
  const float* W_UK  = (const float*)d_in[5];
  const float* W_UV  = (const float*)d_in[6];
  const float* W_KR  = (const float*)d_in[7];
  const float* W_O   = (const float*)d_in[8];

  char* p = (char*)d_ws;
  unsigned short* xb  = (unsigned short*)p; p += (size_t)8192 * 1024 * 2;
  unsigned short* WT1 = (unsigned short*)p; p += (size_t)544 * 1024 * 2;   // [W_DQ^T; W_DKV^T; W_KR^T]
  unsigned short* WT2 = (unsigned short*)p; p += (size_t)1536 * 256 * 2;   // [W_UQ^T; W_QR^T]
  unsigned short* WT3 = (unsigned short*)p; p += (size_t)2048 * 256 * 2;   // [W_UK^T; W_UV^T]
  unsigned short* WT4 = (unsigned short*)p; p += (size_t)1024 * 1024 * 2;  // W_O^T
  unsigned short* C1  = (unsigned short*)p; p += (size_t)8192 * 544 * 2;   // [c_q | c_kv | kr_raw]
  unsigned short* C2  = (unsigned short*)p; p += (size_t)8192 * 1536 * 2;  // [Qc | Qr(roped in-place)]
  unsigned short* C3  = (unsigned short*)p; p += (size_t)8192 * 1024 * 2;  // Kc only
  unsigned short* Krr = (unsigned short*)p; p += (size_t)8192 * 32 * 2;    // roped Kr
  unsigned short* Vt  = (unsigned short*)p; p += (size_t)64 * 64 * 2048 * 2;
  unsigned short* Oa  = (unsigned short*)p; p += (size_t)8192 * 1024 * 2;  // attn out (B,S,1024)

  convert_x<<<8192, 256, 0, stream>>>(x, xb);

  TWArgs tw;
  tw.W[0] = W_DQ;  tw.T[0] = WT1;
  tw.W[1] = W_DKV; tw.T[1] = WT1 + 256 * 1024;
  tw.W[2] = W_KR;  tw.T[2] = WT1 + 512 * 1024;
  tw.W[3] = W_UQ;  tw.T[3] = WT2;
  tw.W[4] = W_QR;  tw.T[4] = WT2 + 1024 * 256;
  tw.W[5] = W_UK;  tw.T[5] = WT3;
  tw.W[6] = W_UV;  tw.T[6] = WT3 + 1024 * 256;
  tw.W[7] = W_O;   tw.T[7] = WT4;
  transpose_w_all<<<2464, 256, 0, stream>>>(tw);

  gemm_bt<true><<<dim3(64, 5),  256, 0, stream>>>(xb, 1024, WT1, 1024, C1, 544, 544, 1024);
  gemm_bt<true><<<dim3(64, 12), 256, 0, stream>>>(C1, 544, WT2, 256, C2, 1536, 1536, 256);
  gemm_bt<true><<<dim3(64, 8),  256, 0, stream>>>(C1 + 256, 544, WT3, 256, C3, 1024, 1024, 256);
  gemm_bt_vt<<<dim3(64, 8),     256, 0, stream>>>(C1 + 256, 544, WT3 + 1024 * 256, 256, Vt, 256);
  rope_qk<<<8704, 256, 0, stream>>>(C2, C1, Krr);
  flash_attn<<<dim3(64, 16), 256, 0, stream>>>(C2, C3, Krr, Vt, Oa);
  gemm_bt<false><<<dim3(64, 8), 256, 0, stream>>>(Oa, 1024, WT4, 1024, d_out, 1024, 1024, 1024);
}